// Round 2
// baseline (19446.175 us; speedup 1.0000x reference)
//
#include <hip/hip_runtime.h>

#define SS 2048
#define BATCH 512
#define NB 1          // batch elements per block (1 -> grid=512 -> 2 blocks/CU)
#define NT 512        // threads per block: 64 j * 8 ko

// ---------- fast fp32 helpers ----------
__device__ __forceinline__ float fast_rcp(float a) { return __builtin_amdgcn_rcpf(a); }
__device__ __forceinline__ float fast_exp2(float a) { return __builtin_amdgcn_exp2f(a); }

// ---------- DPP add (quad xor1 / xor2, row_half_mirror) ----------
template <int CTRL>
__device__ __forceinline__ float dpp_add(float v) {
  const int sh = __builtin_amdgcn_update_dpp(0, __float_as_int(v), CTRL, 0xf, 0xf, true);
  return v + __int_as_float(sh);
}

// ---------- DPP mov (quad_perm broadcast) ----------
template <int CTRL>
__device__ __forceinline__ float dpp_mov(float v) {
  return __int_as_float(__builtin_amdgcn_update_dpp(0, __float_as_int(v), CTRL, 0xf, 0xf, true));
}

// ---------- partial matvec over this thread's 8-wide K slice ----------
__device__ __forceinline__ void mv8(const float (&w)[4][8], const float* hsrc,
                                    float (&acc)[4]) {
  const float4 a = *(const float4*)(hsrc);
  const float4 b = *(const float4*)(hsrc + 4);
  const float hv[8] = {a.x, a.y, a.z, a.w, b.x, b.y, b.z, b.w};
#pragma unroll
  for (int g = 0; g < 4; ++g) {
    float s = acc[g];
#pragma unroll
    for (int kk = 0; kk < 8; ++kk) s = fmaf(w[g][kk], hv[kk], s);
    acc[g] = s;
  }
}

// 2-stage DPP quad reduce (4 gates), select lane's gate, then finish the
// cross-quad (xor4) sum with DPP row_half_mirror: lane q pairs with 7-q.
// Upper-quad lanes select gate 3-(ko&3), so both mirror partners carry the
// SAME gate -> the two addends are bitwise identical to the old xor4 pair.
__device__ __forceinline__ float redsel(float (&a)[4], bool kb0, bool kb1) {
#pragma unroll
  for (int g = 0; g < 4; ++g) {
    a[g] = dpp_add<0xB1>(a[g]);   // quad_perm(1,0,3,2) = xor1
    a[g] = dpp_add<0x4E>(a[g]);   // quad_perm(2,3,0,1) = xor2
  }
  const float s01 = kb0 ? a[1] : a[0];
  const float s23 = kb0 ? a[3] : a[2];
  float s = kb1 ? s23 : s01;            // gate gsel (see kernel init)
  s = dpp_add<0x141>(s);                // row_half_mirror -> full K sum
  return s;
}

// Branchless activation (per-lane consts) + quad-level gate broadcast +
// c/h update. Broadcast values are correct in quad0 (lanes hold gates
// i,f,g,o in order); quad1 lanes produce permuted garbage, but only lane
// ko==0 (in quad0) ever writes h, and c of lanes 4..7 feeds nothing.
__device__ __forceinline__ float gate_finish(float pre, float kact, float aact,
                                             float bact, float& c) {
  const float e = fast_exp2(kact * pre);
  const float r = fast_rcp(1.0f + e);
  const float a = fmaf(aact, r, bact);
  const float vi = dpp_mov<0x00>(a);    // quad_perm(0,0,0,0): gate i
  const float vf = dpp_mov<0x55>(a);    // quad_perm(1,1,1,1): gate f
  const float vg = dpp_mov<0xAA>(a);    // quad_perm(2,2,2,2): gate g
  const float vo = dpp_mov<0xFF>(a);    // quad_perm(3,3,3,3): gate o
  c = fmaf(vf, c, vi * vg);
  const float te = fast_exp2(2.8853900817779268f * c);   // tanh(c)
  const float tr = fast_rcp(1.0f + te);
  const float t = vo * tr;
  return fmaf(-2.0f, t, vo);            // o * tanh(c)
}

// One timestep. Ping-pong parity CUR -> NXT; 2 barriers (hazard analysis
// unchanged: every conflicting write/read pair is separated by >= 2 of the
// per-step barriers).
template <int CUR, int NXT>
__device__ __forceinline__ void lstm_step(
    float (&hb)[2][3][NB][64],
    const float (&whh0)[4][8], const float (&wih1)[4][8],
    const float (&whh1)[4][8], const float (&wih2)[4][8],
    const float (&whh2)[4][8],
    const float (&wi0l)[4],   // per-lane Wih0 row (gate gsel)
    float b0l, float b1l, float b2l,          // per-lane biases
    float kact, float aact, float bact,       // per-lane activation consts
    float (&c0)[NB], float (&c1)[NB], float (&c2)[NB],
    const float (&xin)[NB][4], int j, int ko, int k0,
    bool kb0, bool kb1, bool wr) {
  float p0[NB][4], p1[NB][4];
  // ---- S1: barrier-safe old-h matvecs ----
#pragma unroll
  for (int b = 0; b < NB; ++b) {
#pragma unroll
    for (int g = 0; g < 4; ++g) { p0[b][g] = 0.f; p1[b][g] = 0.f; }
    mv8(whh0, &hb[CUR][0][b][k0], p0[b]);
    mv8(whh1, &hb[CUR][1][b][k0], p1[b]);
  }
  // ---- finish layer 0 (adds per-lane x-projection + bias) ----
#pragma unroll
  for (int b = 0; b < NB; ++b) {
    float s = redsel(p0[b], kb0, kb1);
    float d = b0l;
#pragma unroll
    for (int f2 = 0; f2 < 4; ++f2) d = fmaf(wi0l[f2], xin[b][f2], d);
    const float hn = gate_finish(s + d, kact, aact, bact, c0[b]);
    if (wr) hb[NXT][0][b][j] = hn;
  }
  __syncthreads();  // barrier A
  // ---- layer 1 ----
#pragma unroll
  for (int b = 0; b < NB; ++b) {
    mv8(wih1, &hb[NXT][0][b][k0], p1[b]);
    const float hn = gate_finish(redsel(p1[b], kb0, kb1) + b1l, kact, aact, bact, c1[b]);
    if (wr) hb[NXT][1][b][j] = hn;
  }
  __syncthreads();  // barrier B
  // ---- layer 2 ----
#pragma unroll
  for (int b = 0; b < NB; ++b) {
    float p2[4] = {0.f, 0.f, 0.f, 0.f};
    mv8(wih2, &hb[NXT][1][b][k0], p2);
    mv8(whh2, &hb[CUR][2][b][k0], p2);
    const float hn = gate_finish(redsel(p2, kb0, kb1) + b2l, kact, aact, bact, c2[b]);
    if (wr) hb[NXT][2][b][j] = hn;
  }
}

__global__ void __launch_bounds__(NT, 4)
lstm3_kernel(const float* __restrict__ x,
             const float* __restrict__ Wih0, const float* __restrict__ Whh0,
             const float* __restrict__ bih0, const float* __restrict__ bhh0,
             const float* __restrict__ Wih1, const float* __restrict__ Whh1,
             const float* __restrict__ bih1, const float* __restrict__ bhh1,
             const float* __restrict__ Wih2, const float* __restrict__ Whh2,
             const float* __restrict__ bih2, const float* __restrict__ bhh2,
             const float* __restrict__ fcw, const float* __restrict__ fcb,
             float* __restrict__ out) {
  __shared__ float hb[2][3][NB][64];  // [parity][layer][b][k], 1.5 KB
  const int tid = threadIdx.x;
  const int j = tid >> 3;       // hidden unit 0..63
  const int ko = tid & 7;       // K-octant (lane bits 0..2)
  const int k0 = ko << 3;
  const int bbase = blockIdx.x * NB;
  // Gate selected by this lane after the quad reduce. Upper quad (ko&4)
  // takes the REVERSED gate order so that row_half_mirror (lane q <-> 7-q)
  // pairs identical gates for the cross-quad sum.
  const int gl = (ko & 4) ? (3 - (ko & 3)) : (ko & 3);
  const bool kb0 = (gl & 1) != 0;
  const bool kb1 = (gl & 2) != 0;
  const bool wr = (ko == 0);

  // register-resident weights: 4 gate-rows x 8-wide K slice per matrix
  float whh0[4][8], wih1[4][8], whh1[4][8], wih2[4][8], whh2[4][8];
#pragma unroll
  for (int g = 0; g < 4; ++g) {
    const int r = (g << 6) + j;   // PyTorch gate-order rows: i,f,g,o
    const int ro = (r << 6) + k0;
    *(float4*)&whh0[g][0] = *(const float4*)&Whh0[ro];
    *(float4*)&whh0[g][4] = *(const float4*)&Whh0[ro + 4];
    *(float4*)&wih1[g][0] = *(const float4*)&Wih1[ro];
    *(float4*)&wih1[g][4] = *(const float4*)&Wih1[ro + 4];
    *(float4*)&whh1[g][0] = *(const float4*)&Whh1[ro];
    *(float4*)&whh1[g][4] = *(const float4*)&Whh1[ro + 4];
    *(float4*)&wih2[g][0] = *(const float4*)&Wih2[ro];
    *(float4*)&wih2[g][4] = *(const float4*)&Wih2[ro + 4];
    *(float4*)&whh2[g][0] = *(const float4*)&Whh2[ro];
    *(float4*)&whh2[g][4] = *(const float4*)&Whh2[ro + 4];
  }

  // per-lane gate-specific constants (gate = gl)
  const int rl = (gl << 6) + j;
  const float b0l = bih0[rl] + bhh0[rl];
  const float b1l = bih1[rl] + bhh1[rl];
  const float b2l = bih2[rl] + bhh2[rl];
  float wi0l[4];
  {
    const float4 w0 = *(const float4*)&Wih0[rl * 4];
    wi0l[0] = w0.x; wi0l[1] = w0.y; wi0l[2] = w0.z; wi0l[3] = w0.w;
  }
  const bool isg = (gl == 2);
  const float kact = isg ? 2.8853900817779268f : -1.4426950408889634f;
  const float aact = isg ? -2.0f : 1.0f;
  const float bact = isg ? 1.0f : 0.0f;

  float c0[NB], c1[NB], c2[NB];
#pragma unroll
  for (int b = 0; b < NB; ++b) { c0[b] = 0.f; c1[b] = 0.f; c2[b] = 0.f; }

  {  // zero both parities of h
    float* p = &hb[0][0][0][0];
    for (int i = tid; i < 2 * 3 * NB * 64; i += NT) p[i] = 0.f;
  }

  // x prefetch (full 4-vector per batch elem, double-buffered)
  float xc[NB][4], xn[NB][4];
#pragma unroll
  for (int b = 0; b < NB; ++b) {
    const float4 v = *(const float4*)&x[(size_t)(bbase + b) * SS * 4];
    xc[b][0] = v.x; xc[b][1] = v.y; xc[b][2] = v.z; xc[b][3] = v.w;
  }
  __syncthreads();

#pragma unroll 1
  for (int t = 0; t < SS; t += 2) {
#pragma unroll
    for (int b = 0; b < NB; ++b) {
      const float4 v = *(const float4*)&x[((size_t)(bbase + b) * SS + (t + 1)) * 4];
      xn[b][0] = v.x; xn[b][1] = v.y; xn[b][2] = v.z; xn[b][3] = v.w;
    }
    lstm_step<0, 1>(hb, whh0, wih1, whh1, wih2, whh2, wi0l, b0l, b1l, b2l,
                    kact, aact, bact, c0, c1, c2, xc, j, ko, k0, kb0, kb1, wr);
    const int tp = (t + 2 < SS) ? (t + 2) : (SS - 1);
#pragma unroll
    for (int b = 0; b < NB; ++b) {
      const float4 v = *(const float4*)&x[((size_t)(bbase + b) * SS + tp) * 4];
      xc[b][0] = v.x; xc[b][1] = v.y; xc[b][2] = v.z; xc[b][3] = v.w;
    }
    lstm_step<1, 0>(hb, whh0, wih1, whh1, wih2, whh2, wi0l, b0l, b1l, b2l,
                    kact, aact, bact, c0, c1, c2, xn, j, ko, k0, kb0, kb1, wr);
  }
  __syncthreads();  // publish final h2 (parity 0 after t=2047)

  // fc: out[b][o] = fc_b[o] + sum_j fc_w[o][j] * h2_last[b][j]
  if (tid < NB * 2) {
    const int b = tid >> 1, o = tid & 1;
    float s = fcb[o];
#pragma unroll
    for (int jj = 0; jj < 64; ++jj)
      s = fmaf(fcw[o * 64 + jj], hb[0][2][b][jj], s);
    out[(bbase + b) * 2 + o] = s;
  }
}

extern "C" void kernel_launch(void* const* d_in, const int* in_sizes, int n_in,
                              void* d_out, int out_size, void* d_ws, size_t ws_size,
                              hipStream_t stream) {
  const float* x    = (const float*)d_in[0];
  const float* Wih0 = (const float*)d_in[1];
  const float* Whh0 = (const float*)d_in[2];
  const float* bih0 = (const float*)d_in[3];
  const float* bhh0 = (const float*)d_in[4];
  const float* Wih1 = (const float*)d_in[5];
  const float* Whh1 = (const float*)d_in[6];
  const float* bih1 = (const float*)d_in[7];
  const float* bhh1 = (const float*)d_in[8];
  const float* Wih2 = (const float*)d_in[9];
  const float* Whh2 = (const float*)d_in[10];
  const float* bih2 = (const float*)d_in[11];
  const float* bhh2 = (const float*)d_in[12];
  const float* fcw  = (const float*)d_in[13];
  const float* fcb  = (const float*)d_in[14];
  float* out = (float*)d_out;

  lstm3_kernel<<<dim3(BATCH / NB), dim3(NT), 0, stream>>>(
      x, Wih0, Whh0, bih0, bhh0, Wih1, Whh1, bih1, bhh1,
      Wih2, Whh2, bih2, bhh2, fcw, fcb, out);
}

// Round 3
// 4019.206 us; speedup vs baseline: 4.8383x; 4.8383x over previous
//
#include <hip/hip_runtime.h>

#define SS 2048
#define BATCH 512
#define NB 2          // batch elements per block
#define NT 512        // threads per block: 64 j * 8 ko

// ---------- fast fp32 helpers ----------
__device__ __forceinline__ float fast_rcp(float a) { return __builtin_amdgcn_rcpf(a); }
__device__ __forceinline__ float fast_exp2(float a) { return __builtin_amdgcn_exp2f(a); }

// ---------- DPP add (quad xor1 / xor2, row_half_mirror) ----------
template <int CTRL>
__device__ __forceinline__ float dpp_add(float v) {
  const int sh = __builtin_amdgcn_update_dpp(0, __float_as_int(v), CTRL, 0xf, 0xf, true);
  return v + __int_as_float(sh);
}

// ---------- DPP mov (quad_perm broadcast) ----------
template <int CTRL>
__device__ __forceinline__ float dpp_mov(float v) {
  return __int_as_float(__builtin_amdgcn_update_dpp(0, __float_as_int(v), CTRL, 0xf, 0xf, true));
}

// ---------- partial matvec over this thread's 8-wide K slice ----------
__device__ __forceinline__ void mv8(const float (&w)[4][8], const float* hsrc,
                                    float (&acc)[4]) {
  const float4 a = *(const float4*)(hsrc);
  const float4 b = *(const float4*)(hsrc + 4);
  const float hv[8] = {a.x, a.y, a.z, a.w, b.x, b.y, b.z, b.w};
#pragma unroll
  for (int g = 0; g < 4; ++g) {
    float s = acc[g];
#pragma unroll
    for (int kk = 0; kk < 8; ++kk) s = fmaf(w[g][kk], hv[kk], s);
    acc[g] = s;
  }
}

// 2-stage DPP quad reduce (4 gates), select lane's gate, then finish the
// cross-quad (xor4) sum with DPP row_half_mirror: lane q pairs with 7-q.
// Upper-quad lanes select gate 3-(ko&3), so both mirror partners carry the
// SAME gate -> the two addends are bitwise identical to the old xor4 pair.
__device__ __forceinline__ float redsel(float (&a)[4], bool kb0, bool kb1) {
#pragma unroll
  for (int g = 0; g < 4; ++g) {
    a[g] = dpp_add<0xB1>(a[g]);   // quad_perm(1,0,3,2) = xor1
    a[g] = dpp_add<0x4E>(a[g]);   // quad_perm(2,3,0,1) = xor2
  }
  const float s01 = kb0 ? a[1] : a[0];
  const float s23 = kb0 ? a[3] : a[2];
  float s = kb1 ? s23 : s01;            // gate gsel (see kernel init)
  s = dpp_add<0x141>(s);                // row_half_mirror -> full K sum
  return s;
}

// Branchless activation (per-lane consts) + quad-level gate broadcast +
// c/h update. Broadcast values are correct in quad0 (lanes hold gates
// i,f,g,o in order); quad1 lanes produce permuted garbage, but only lane
// ko==0 (in quad0) ever writes h, and c of lanes 4..7 feeds nothing.
__device__ __forceinline__ float gate_finish(float pre, float kact, float aact,
                                             float bact, float& c) {
  const float e = fast_exp2(kact * pre);
  const float r = fast_rcp(1.0f + e);
  const float a = fmaf(aact, r, bact);
  const float vi = dpp_mov<0x00>(a);    // quad_perm(0,0,0,0): gate i
  const float vf = dpp_mov<0x55>(a);    // quad_perm(1,1,1,1): gate f
  const float vg = dpp_mov<0xAA>(a);    // quad_perm(2,2,2,2): gate g
  const float vo = dpp_mov<0xFF>(a);    // quad_perm(3,3,3,3): gate o
  c = fmaf(vf, c, vi * vg);
  const float te = fast_exp2(2.8853900817779268f * c);   // tanh(c)
  const float tr = fast_rcp(1.0f + te);
  const float t = vo * tr;
  return fmaf(-2.0f, t, vo);            // o * tanh(c)
}

// One DIAGONAL superstep: compute h0(s), h1(s-1), h2(s-2) in parallel.
// Every matvec reads parity CUR (previous superstep's outputs); every
// result writes parity NXT. Single barrier at the end: it separates
// {reads of CUR, writes of NXT} from next superstep's {reads of NXT,
// writes of CUR} -> no WAR/RAW hazard with the ping-pong double buffer.
// act0/act1/act2 gate the c-update + h-write during pipeline fill/drain.
template <int CUR, int NXT>
__device__ __forceinline__ void lstm_step(
    float (&hb)[2][3][NB][64],
    const float (&whh0)[4][8], const float (&wih1)[4][8],
    const float (&whh1)[4][8], const float (&wih2)[4][8],
    const float (&whh2)[4][8],
    const float (&wi0l)[4],   // per-lane Wih0 row (gate gsel)
    float b0l, float b1l, float b2l,          // per-lane biases
    float kact, float aact, float bact,       // per-lane activation consts
    float (&c0)[NB], float (&c1)[NB], float (&c2)[NB],
    const float (&xin)[NB][4], int j, int k0,
    bool kb0, bool kb1, bool wr,
    bool act0, bool act1, bool act2) {
  float p0[NB][4], p1[NB][4], p2[NB][4];
  // ---- all 5 matvecs, all reading CUR ----
#pragma unroll
  for (int b = 0; b < NB; ++b) {
#pragma unroll
    for (int g = 0; g < 4; ++g) { p0[b][g] = 0.f; p1[b][g] = 0.f; p2[b][g] = 0.f; }
    mv8(whh0, &hb[CUR][0][b][k0], p0[b]);   // L0: h0(s-1)
    mv8(wih1, &hb[CUR][0][b][k0], p1[b]);   // L1: h0(s-1)
    mv8(whh1, &hb[CUR][1][b][k0], p1[b]);   // L1: h1(s-2)
    mv8(wih2, &hb[CUR][1][b][k0], p2[b]);   // L2: h1(s-2)
    mv8(whh2, &hb[CUR][2][b][k0], p2[b]);   // L2: h2(s-3)
  }
  // ---- finish all three layers (independent chains) ----
#pragma unroll
  for (int b = 0; b < NB; ++b) {
    // L0 (adds per-lane x-projection + bias)
    float s0 = redsel(p0[b], kb0, kb1);
    float d = b0l;
#pragma unroll
    for (int f2 = 0; f2 < 4; ++f2) d = fmaf(wi0l[f2], xin[b][f2], d);
    float cc0 = c0[b];
    const float h0 = gate_finish(s0 + d, kact, aact, bact, cc0);
    if (act0) { c0[b] = cc0; if (wr) hb[NXT][0][b][j] = h0; }
    // L1
    float cc1 = c1[b];
    const float h1 = gate_finish(redsel(p1[b], kb0, kb1) + b1l, kact, aact, bact, cc1);
    if (act1) { c1[b] = cc1; if (wr) hb[NXT][1][b][j] = h1; }
    // L2
    float cc2 = c2[b];
    const float h2 = gate_finish(redsel(p2[b], kb0, kb1) + b2l, kact, aact, bact, cc2);
    if (act2) { c2[b] = cc2; if (wr) hb[NXT][2][b][j] = h2; }
  }
  __syncthreads();  // single barrier per superstep
}

__global__ void __launch_bounds__(NT, 2)
lstm3_kernel(const float* __restrict__ x,
             const float* __restrict__ Wih0, const float* __restrict__ Whh0,
             const float* __restrict__ bih0, const float* __restrict__ bhh0,
             const float* __restrict__ Wih1, const float* __restrict__ Whh1,
             const float* __restrict__ bih1, const float* __restrict__ bhh1,
             const float* __restrict__ Wih2, const float* __restrict__ Whh2,
             const float* __restrict__ bih2, const float* __restrict__ bhh2,
             const float* __restrict__ fcw, const float* __restrict__ fcb,
             float* __restrict__ out) {
  __shared__ float hb[2][3][NB][64];  // [parity][layer][b][k], 3 KB
  const int tid = threadIdx.x;
  const int j = tid >> 3;       // hidden unit 0..63
  const int ko = tid & 7;       // K-octant (lane bits 0..2)
  const int k0 = ko << 3;
  const int bbase = blockIdx.x * NB;
  // Gate selected by this lane after the quad reduce. Upper quad (ko&4)
  // takes the REVERSED gate order so that row_half_mirror (lane q <-> 7-q)
  // pairs identical gates for the cross-quad sum.
  const int gl = (ko & 4) ? (3 - (ko & 3)) : (ko & 3);
  const bool kb0 = (gl & 1) != 0;
  const bool kb1 = (gl & 2) != 0;
  const bool wr = (ko == 0);

  // register-resident weights: 4 gate-rows x 8-wide K slice per matrix
  float whh0[4][8], wih1[4][8], whh1[4][8], wih2[4][8], whh2[4][8];
#pragma unroll
  for (int g = 0; g < 4; ++g) {
    const int r = (g << 6) + j;   // PyTorch gate-order rows: i,f,g,o
    const int ro = (r << 6) + k0;
    *(float4*)&whh0[g][0] = *(const float4*)&Whh0[ro];
    *(float4*)&whh0[g][4] = *(const float4*)&Whh0[ro + 4];
    *(float4*)&wih1[g][0] = *(const float4*)&Wih1[ro];
    *(float4*)&wih1[g][4] = *(const float4*)&Wih1[ro + 4];
    *(float4*)&whh1[g][0] = *(const float4*)&Whh1[ro];
    *(float4*)&whh1[g][4] = *(const float4*)&Whh1[ro + 4];
    *(float4*)&wih2[g][0] = *(const float4*)&Wih2[ro];
    *(float4*)&wih2[g][4] = *(const float4*)&Wih2[ro + 4];
    *(float4*)&whh2[g][0] = *(const float4*)&Whh2[ro];
    *(float4*)&whh2[g][4] = *(const float4*)&Whh2[ro + 4];
  }

  // per-lane gate-specific constants (gate = gl)
  const int rl = (gl << 6) + j;
  const float b0l = bih0[rl] + bhh0[rl];
  const float b1l = bih1[rl] + bhh1[rl];
  const float b2l = bih2[rl] + bhh2[rl];
  float wi0l[4];
  {
    const float4 w0 = *(const float4*)&Wih0[rl * 4];
    wi0l[0] = w0.x; wi0l[1] = w0.y; wi0l[2] = w0.z; wi0l[3] = w0.w;
  }
  const bool isg = (gl == 2);
  const float kact = isg ? 2.8853900817779268f : -1.4426950408889634f;
  const float aact = isg ? -2.0f : 1.0f;
  const float bact = isg ? 1.0f : 0.0f;

  float c0[NB], c1[NB], c2[NB];
#pragma unroll
  for (int b = 0; b < NB; ++b) { c0[b] = 0.f; c1[b] = 0.f; c2[b] = 0.f; }

  {  // zero both parities of h (fill steps read zeros for upper layers)
    float* p = &hb[0][0][0][0];
    for (int i = tid; i < 2 * 3 * NB * 64; i += NT) p[i] = 0.f;
  }

  // x prefetch (full 4-vector per batch elem, double-buffered)
  float xc[NB][4], xn[NB][4];
#pragma unroll
  for (int b = 0; b < NB; ++b) {
    const float4 v = *(const float4*)&x[(size_t)(bbase + b) * SS * 4];
    xc[b][0] = v.x; xc[b][1] = v.y; xc[b][2] = v.z; xc[b][3] = v.w;
  }
  __syncthreads();

  // SS+2 supersteps (2 extra for pipeline fill/drain). Superstep s:
  //   L0 computes h0(s)    -- active s < SS
  //   L1 computes h1(s-1)  -- active 1 <= s <= SS
  //   L2 computes h2(s-2)  -- active s >= 2   (last: s = SS+1)
#pragma unroll 1
  for (int t = 0; t < SS + 2; t += 2) {
    {
      const int i1 = (t + 1 < SS) ? (t + 1) : (SS - 1);
#pragma unroll
      for (int b = 0; b < NB; ++b) {
        const float4 v = *(const float4*)&x[((size_t)(bbase + b) * SS + i1) * 4];
        xn[b][0] = v.x; xn[b][1] = v.y; xn[b][2] = v.z; xn[b][3] = v.w;
      }
    }
    lstm_step<0, 1>(hb, whh0, wih1, whh1, wih2, whh2, wi0l, b0l, b1l, b2l,
                    kact, aact, bact, c0, c1, c2, xc, j, k0, kb0, kb1, wr,
                    /*act0=*/t < SS, /*act1=*/(t >= 1) && (t <= SS),
                    /*act2=*/t >= 2);
    {
      const int i2 = (t + 2 < SS) ? (t + 2) : (SS - 1);
#pragma unroll
      for (int b = 0; b < NB; ++b) {
        const float4 v = *(const float4*)&x[((size_t)(bbase + b) * SS + i2) * 4];
        xc[b][0] = v.x; xc[b][1] = v.y; xc[b][2] = v.z; xc[b][3] = v.w;
      }
    }
    lstm_step<1, 0>(hb, whh0, wih1, whh1, wih2, whh2, wi0l, b0l, b1l, b2l,
                    kact, aact, bact, c0, c1, c2, xn, j, k0, kb0, kb1, wr,
                    /*act0=*/t + 1 < SS, /*act1=*/t + 1 <= SS,
                    /*act2=*/t + 1 >= 2);
  }
  // Last superstep is s = SS+1 (odd), writes parity 0: h2(SS-1) in hb[0][2].
  __syncthreads();

  // fc: out[b][o] = fc_b[o] + sum_j fc_w[o][j] * h2_last[b][j]
  if (tid < NB * 2) {
    const int b = tid >> 1, o = tid & 1;
    float s = fcb[o];
#pragma unroll
    for (int jj = 0; jj < 64; ++jj)
      s = fmaf(fcw[o * 64 + jj], hb[0][2][b][jj], s);
    out[(bbase + b) * 2 + o] = s;
  }
}

extern "C" void kernel_launch(void* const* d_in, const int* in_sizes, int n_in,
                              void* d_out, int out_size, void* d_ws, size_t ws_size,
                              hipStream_t stream) {
  const float* x    = (const float*)d_in[0];
  const float* Wih0 = (const float*)d_in[1];
  const float* Whh0 = (const float*)d_in[2];
  const float* bih0 = (const float*)d_in[3];
  const float* bhh0 = (const float*)d_in[4];
  const float* Wih1 = (const float*)d_in[5];
  const float* Whh1 = (const float*)d_in[6];
  const float* bih1 = (const float*)d_in[7];
  const float* bhh1 = (const float*)d_in[8];
  const float* Wih2 = (const float*)d_in[9];
  const float* Whh2 = (const float*)d_in[10];
  const float* bih2 = (const float*)d_in[11];
  const float* bhh2 = (const float*)d_in[12];
  const float* fcw  = (const float*)d_in[13];
  const float* fcb  = (const float*)d_in[14];
  float* out = (float*)d_out;

  lstm3_kernel<<<dim3(BATCH / NB), dim3(NT), 0, stream>>>(
      x, Wih0, Whh0, bih0, bhh0, Wih1, Whh1, bih1, bhh1,
      Wih2, Whh2, bih2, bhh2, fcw, fcb, out);
}

// Round 4
// 3667.563 us; speedup vs baseline: 5.3022x; 1.0959x over previous
//
#include <hip/hip_runtime.h>

#define SS 2048
#define BATCH 512
#define NB 2          // batch elements per block
#define NT 512        // threads per block: 64 j * 8 ko

typedef float f2 __attribute__((ext_vector_type(2)));

// ---------- fast fp32 helpers ----------
__device__ __forceinline__ float fast_rcp(float a) { return __builtin_amdgcn_rcpf(a); }
__device__ __forceinline__ float fast_exp2(float a) { return __builtin_amdgcn_exp2f(a); }

// ---------- packed fp32 (VOP3P, full-rate dual FMA on gfx950) ----------
__device__ __forceinline__ f2 pk_fma(f2 a, f2 b, f2 c) {
  f2 d;
  asm("v_pk_fma_f32 %0, %1, %2, %3" : "=v"(d) : "v"(a), "v"(b), "v"(c));
  return d;
}
__device__ __forceinline__ f2 pk_mul(f2 a, f2 b) {
  f2 d;
  asm("v_pk_mul_f32 %0, %1, %2" : "=v"(d) : "v"(a), "v"(b));
  return d;
}

// ---------- DPP add (quad xor1 / xor2, row_half_mirror) ----------
template <int CTRL>
__device__ __forceinline__ float dpp_add(float v) {
  const int sh = __builtin_amdgcn_update_dpp(0, __float_as_int(v), CTRL, 0xf, 0xf, true);
  return v + __int_as_float(sh);
}

// ---------- DPP mov (quad_perm broadcast) ----------
template <int CTRL>
__device__ __forceinline__ float dpp_mov(float v) {
  return __int_as_float(__builtin_amdgcn_update_dpp(0, __float_as_int(v), CTRL, 0xf, 0xf, true));
}

// ---------- load this thread's 8-wide h slice as 4 packed pairs ----------
__device__ __forceinline__ void ld8(const float* p, f2 (&hv)[4]) {
  const float4 A = *(const float4*)p;
  const float4 B = *(const float4*)(p + 4);
  hv[0] = f2{A.x, A.y}; hv[1] = f2{A.z, A.w};
  hv[2] = f2{B.x, B.y}; hv[3] = f2{B.z, B.w};
}

// ---------- packed matvec over the 8-wide K slice (4 gates) ----------
// First-use variant: acc = w*h exactly (fma with 0 addend == rounded mul).
__device__ __forceinline__ void mv8p_first(const f2 (&w)[4][4], const f2 (&hv)[4],
                                           f2 (&acc)[4]) {
#pragma unroll
  for (int g = 0; g < 4; ++g) {
    acc[g] = pk_mul(w[g][0], hv[0]);
#pragma unroll
    for (int k = 1; k < 4; ++k) acc[g] = pk_fma(w[g][k], hv[k], acc[g]);
  }
}
__device__ __forceinline__ void mv8p(const f2 (&w)[4][4], const f2 (&hv)[4],
                                     f2 (&acc)[4]) {
#pragma unroll
  for (int g = 0; g < 4; ++g) {
#pragma unroll
    for (int k = 0; k < 4; ++k) acc[g] = pk_fma(w[g][k], hv[k], acc[g]);
  }
}

// Collapse packed lo/hi, 2-stage DPP quad reduce (4 gates), select lane's
// gate, then finish the cross-quad (xor4) sum with DPP row_half_mirror:
// lane q pairs with 7-q. Upper-quad lanes select gate 3-(ko&3), so both
// mirror partners carry the SAME gate.
__device__ __forceinline__ float redsel(f2 (&a2)[4], bool kb0, bool kb1) {
  float a[4];
#pragma unroll
  for (int g = 0; g < 4; ++g) a[g] = a2[g].x + a2[g].y;
#pragma unroll
  for (int g = 0; g < 4; ++g) {
    a[g] = dpp_add<0xB1>(a[g]);   // quad_perm(1,0,3,2) = xor1
    a[g] = dpp_add<0x4E>(a[g]);   // quad_perm(2,3,0,1) = xor2
  }
  const float s01 = kb0 ? a[1] : a[0];
  const float s23 = kb0 ? a[3] : a[2];
  float s = kb1 ? s23 : s01;            // gate gsel (see kernel init)
  s = dpp_add<0x141>(s);                // row_half_mirror -> full K sum
  return s;
}

// Branchless activation (per-lane consts) + quad-level gate broadcast +
// c/h update. Correct in quad0; quad1 garbage is never committed (wr lane
// is in quad0, c of lanes 4..7 feeds nothing).
__device__ __forceinline__ float gate_finish(float pre, float kact, float aact,
                                             float bact, float& c) {
  const float e = fast_exp2(kact * pre);
  const float r = fast_rcp(1.0f + e);
  const float a = fmaf(aact, r, bact);
  const float vi = dpp_mov<0x00>(a);    // quad_perm(0,0,0,0): gate i
  const float vf = dpp_mov<0x55>(a);    // quad_perm(1,1,1,1): gate f
  const float vg = dpp_mov<0xAA>(a);    // quad_perm(2,2,2,2): gate g
  const float vo = dpp_mov<0xFF>(a);    // quad_perm(3,3,3,3): gate o
  c = fmaf(vf, c, vi * vg);
  const float te = fast_exp2(2.8853900817779268f * c);   // tanh(c)
  const float tr = fast_rcp(1.0f + te);
  const float t = vo * tr;
  return fmaf(-2.0f, t, vo);            // o * tanh(c)
}

// One DIAGONAL superstep: compute h0(s), h1(s-1), h2(s-2) in parallel.
// Every matvec reads parity CUR; every result writes parity NXT. Single
// barrier at the end. h0/h1 each loaded ONCE and shared by both consumers.
// act0/act1/act2 gate the c-update + h-write during pipeline fill/drain.
template <int CUR, int NXT>
__device__ __forceinline__ void lstm_step(
    float (&hb)[2][3][NB][64],
    const f2 (&whh0)[4][4], const f2 (&wih1)[4][4],
    const f2 (&whh1)[4][4], const f2 (&wih2)[4][4],
    const f2 (&whh2)[4][4],
    const float (&wi0l)[4],   // per-lane Wih0 row (gate gsel)
    float b0l, float b1l, float b2l,          // per-lane biases
    float kact, float aact, float bact,       // per-lane activation consts
    float (&c0)[NB], float (&c1)[NB], float (&c2)[NB],
    const float (&xin)[NB][4], int j, int k0,
    bool kb0, bool kb1, bool wr,
    bool act0, bool act1, bool act2) {
  f2 p0[NB][4], p1[NB][4], p2[NB][4];
  // ---- all 5 matvecs, all reading CUR; h slices loaded once ----
#pragma unroll
  for (int b = 0; b < NB; ++b) {
    f2 hv0[4], hv1[4], hv2[4];
    ld8(&hb[CUR][0][b][k0], hv0);
    ld8(&hb[CUR][1][b][k0], hv1);
    ld8(&hb[CUR][2][b][k0], hv2);
    mv8p_first(whh0, hv0, p0[b]);   // L0: h0(s-1)
    mv8p_first(wih1, hv0, p1[b]);   // L1: h0(s-1)
    mv8p      (whh1, hv1, p1[b]);   // L1: h1(s-2)
    mv8p_first(wih2, hv1, p2[b]);   // L2: h1(s-2)
    mv8p      (whh2, hv2, p2[b]);   // L2: h2(s-3)
  }
  // ---- finish all three layers (independent chains) ----
#pragma unroll
  for (int b = 0; b < NB; ++b) {
    // L0 (adds per-lane x-projection + bias)
    float s0 = redsel(p0[b], kb0, kb1);
    float d = b0l;
#pragma unroll
    for (int f2i = 0; f2i < 4; ++f2i) d = fmaf(wi0l[f2i], xin[b][f2i], d);
    float cc0 = c0[b];
    const float h0 = gate_finish(s0 + d, kact, aact, bact, cc0);
    if (act0) { c0[b] = cc0; if (wr) hb[NXT][0][b][j] = h0; }
    // L1
    float cc1 = c1[b];
    const float h1 = gate_finish(redsel(p1[b], kb0, kb1) + b1l, kact, aact, bact, cc1);
    if (act1) { c1[b] = cc1; if (wr) hb[NXT][1][b][j] = h1; }
    // L2
    float cc2 = c2[b];
    const float h2 = gate_finish(redsel(p2[b], kb0, kb1) + b2l, kact, aact, bact, cc2);
    if (act2) { c2[b] = cc2; if (wr) hb[NXT][2][b][j] = h2; }
  }
  __syncthreads();  // single barrier per superstep
}

__global__ void __launch_bounds__(NT, 2)
lstm3_kernel(const float* __restrict__ x,
             const float* __restrict__ Wih0, const float* __restrict__ Whh0,
             const float* __restrict__ bih0, const float* __restrict__ bhh0,
             const float* __restrict__ Wih1, const float* __restrict__ Whh1,
             const float* __restrict__ bih1, const float* __restrict__ bhh1,
             const float* __restrict__ Wih2, const float* __restrict__ Whh2,
             const float* __restrict__ bih2, const float* __restrict__ bhh2,
             const float* __restrict__ fcw, const float* __restrict__ fcb,
             float* __restrict__ out) {
  __shared__ float hb[2][3][NB][64];  // [parity][layer][b][k], 3 KB
  const int tid = threadIdx.x;
  const int j = tid >> 3;       // hidden unit 0..63
  const int ko = tid & 7;       // K-octant (lane bits 0..2)
  const int k0 = ko << 3;
  const int bbase = blockIdx.x * NB;
  // Gate selected by this lane after the quad reduce. Upper quad (ko&4)
  // takes the REVERSED gate order so that row_half_mirror (lane q <-> 7-q)
  // pairs identical gates for the cross-quad sum.
  const int gl = (ko & 4) ? (3 - (ko & 3)) : (ko & 3);
  const bool kb0 = (gl & 1) != 0;
  const bool kb1 = (gl & 2) != 0;
  const bool wr = (ko == 0);

  // register-resident weights: 4 gate-rows x 8-wide K slice per matrix,
  // stored as packed f2 pairs for v_pk_fma_f32
  f2 whh0[4][4], wih1[4][4], whh1[4][4], wih2[4][4], whh2[4][4];
#pragma unroll
  for (int g = 0; g < 4; ++g) {
    const int r = (g << 6) + j;   // PyTorch gate-order rows: i,f,g,o
    const int ro = (r << 6) + k0;
#define LDW(dst, srcp)                                            \
    {                                                             \
      const float4 A = *(const float4*)&(srcp)[ro];               \
      const float4 B = *(const float4*)&(srcp)[ro + 4];           \
      dst[g][0] = f2{A.x, A.y}; dst[g][1] = f2{A.z, A.w};         \
      dst[g][2] = f2{B.x, B.y}; dst[g][3] = f2{B.z, B.w};         \
    }
    LDW(whh0, Whh0)
    LDW(wih1, Wih1)
    LDW(whh1, Whh1)
    LDW(wih2, Wih2)
    LDW(whh2, Whh2)
#undef LDW
  }

  // per-lane gate-specific constants (gate = gl)
  const int rl = (gl << 6) + j;
  const float b0l = bih0[rl] + bhh0[rl];
  const float b1l = bih1[rl] + bhh1[rl];
  const float b2l = bih2[rl] + bhh2[rl];
  float wi0l[4];
  {
    const float4 w0 = *(const float4*)&Wih0[rl * 4];
    wi0l[0] = w0.x; wi0l[1] = w0.y; wi0l[2] = w0.z; wi0l[3] = w0.w;
  }
  const bool isg = (gl == 2);
  const float kact = isg ? 2.8853900817779268f : -1.4426950408889634f;
  const float aact = isg ? -2.0f : 1.0f;
  const float bact = isg ? 1.0f : 0.0f;

  float c0[NB], c1[NB], c2[NB];
#pragma unroll
  for (int b = 0; b < NB; ++b) { c0[b] = 0.f; c1[b] = 0.f; c2[b] = 0.f; }

  {  // zero both parities of h (fill steps read zeros for upper layers)
    float* p = &hb[0][0][0][0];
    for (int i = tid; i < 2 * 3 * NB * 64; i += NT) p[i] = 0.f;
  }

  // x prefetch (full 4-vector per batch elem, double-buffered)
  float xc[NB][4], xn[NB][4];
#pragma unroll
  for (int b = 0; b < NB; ++b) {
    const float4 v = *(const float4*)&x[(size_t)(bbase + b) * SS * 4];
    xc[b][0] = v.x; xc[b][1] = v.y; xc[b][2] = v.z; xc[b][3] = v.w;
  }
  __syncthreads();

  // SS+2 supersteps (2 extra for pipeline fill/drain). Superstep s:
  //   L0 computes h0(s)    -- active s < SS
  //   L1 computes h1(s-1)  -- active 1 <= s <= SS
  //   L2 computes h2(s-2)  -- active s >= 2   (last: s = SS+1)
#pragma unroll 1
  for (int t = 0; t < SS + 2; t += 2) {
    {
      const int i1 = (t + 1 < SS) ? (t + 1) : (SS - 1);
#pragma unroll
      for (int b = 0; b < NB; ++b) {
        const float4 v = *(const float4*)&x[((size_t)(bbase + b) * SS + i1) * 4];
        xn[b][0] = v.x; xn[b][1] = v.y; xn[b][2] = v.z; xn[b][3] = v.w;
      }
    }
    lstm_step<0, 1>(hb, whh0, wih1, whh1, wih2, whh2, wi0l, b0l, b1l, b2l,
                    kact, aact, bact, c0, c1, c2, xc, j, k0, kb0, kb1, wr,
                    /*act0=*/t < SS, /*act1=*/(t >= 1) && (t <= SS),
                    /*act2=*/t >= 2);
    {
      const int i2 = (t + 2 < SS) ? (t + 2) : (SS - 1);
#pragma unroll
      for (int b = 0; b < NB; ++b) {
        const float4 v = *(const float4*)&x[((size_t)(bbase + b) * SS + i2) * 4];
        xc[b][0] = v.x; xc[b][1] = v.y; xc[b][2] = v.z; xc[b][3] = v.w;
      }
    }
    lstm_step<1, 0>(hb, whh0, wih1, whh1, wih2, whh2, wi0l, b0l, b1l, b2l,
                    kact, aact, bact, c0, c1, c2, xn, j, k0, kb0, kb1, wr,
                    /*act0=*/t + 1 < SS, /*act1=*/t + 1 <= SS,
                    /*act2=*/t + 1 >= 2);
  }
  // Last superstep is s = SS+1 (odd), writes parity 0: h2(SS-1) in hb[0][2].
  __syncthreads();

  // fc: out[b][o] = fc_b[o] + sum_j fc_w[o][j] * h2_last[b][j]
  if (tid < NB * 2) {
    const int b = tid >> 1, o = tid & 1;
    float s = fcb[o];
#pragma unroll
    for (int jj = 0; jj < 64; ++jj)
      s = fmaf(fcw[o * 64 + jj], hb[0][2][b][jj], s);
    out[(bbase + b) * 2 + o] = s;
  }
}

extern "C" void kernel_launch(void* const* d_in, const int* in_sizes, int n_in,
                              void* d_out, int out_size, void* d_ws, size_t ws_size,
                              hipStream_t stream) {
  const float* x    = (const float*)d_in[0];
  const float* Wih0 = (const float*)d_in[1];
  const float* Whh0 = (const float*)d_in[2];
  const float* bih0 = (const float*)d_in[3];
  const float* bhh0 = (const float*)d_in[4];
  const float* Wih1 = (const float*)d_in[5];
  const float* Whh1 = (const float*)d_in[6];
  const float* bih1 = (const float*)d_in[7];
  const float* bhh1 = (const float*)d_in[8];
  const float* Wih2 = (const float*)d_in[9];
  const float* Whh2 = (const float*)d_in[10];
  const float* bih2 = (const float*)d_in[11];
  const float* bhh2 = (const float*)d_in[12];
  const float* fcw  = (const float*)d_in[13];
  const float* fcb  = (const float*)d_in[14];
  float* out = (float*)d_out;

  lstm3_kernel<<<dim3(BATCH / NB), dim3(NT), 0, stream>>>(
      x, Wih0, Whh0, bih0, bhh0, Wih1, Whh1, bih1, bhh1,
      Wih2, Whh2, bih2, bhh2, fcw, fcb, out);
}

// Round 5
// 3468.467 us; speedup vs baseline: 5.6066x; 1.0574x over previous
//
#include <hip/hip_runtime.h>

#define SS 2048
#define BATCH 512
#define NB 2          // batch elements per block
#define NT 512        // threads per block: 64 j * 8 ko

typedef float f2 __attribute__((ext_vector_type(2)));

// ---------- fast fp32 helpers ----------
__device__ __forceinline__ float fast_rcp(float a) { return __builtin_amdgcn_rcpf(a); }
__device__ __forceinline__ float fast_exp2(float a) { return __builtin_amdgcn_exp2f(a); }

// ---------- packed fp32 via native vector ops ----------
// llvm.fma.v2f32 -> v_pk_fma_f32 on gfx950 (no asm marshalling movs; if the
// backend scalarizes it emits 2x v_fma_f32 with bit-identical results).
__device__ __forceinline__ f2 pk_fma(f2 a, f2 b, f2 c) {
  return __builtin_elementwise_fma(a, b, c);
}
__device__ __forceinline__ f2 pk_mul(f2 a, f2 b) { return a * b; }

// ---------- DPP add (quad xor1 / xor2, row_half_mirror) ----------
template <int CTRL>
__device__ __forceinline__ float dpp_add(float v) {
  const int sh = __builtin_amdgcn_update_dpp(0, __float_as_int(v), CTRL, 0xf, 0xf, true);
  return v + __int_as_float(sh);
}

// ---------- DPP mov (quad_perm broadcast) ----------
template <int CTRL>
__device__ __forceinline__ float dpp_mov(float v) {
  return __int_as_float(__builtin_amdgcn_update_dpp(0, __float_as_int(v), CTRL, 0xf, 0xf, true));
}

// ---------- load this thread's 8-wide h slice as 4 packed pairs ----------
__device__ __forceinline__ void ld8(const float* p, f2 (&hv)[4]) {
  const float4 A = *(const float4*)p;
  const float4 B = *(const float4*)(p + 4);
  hv[0] = f2{A.x, A.y}; hv[1] = f2{A.z, A.w};
  hv[2] = f2{B.x, B.y}; hv[3] = f2{B.z, B.w};
}

// ---------- packed matvec over the 8-wide K slice (4 gates) ----------
// First-use variant: acc = w*h exactly (same rounding as fma with 0 addend).
__device__ __forceinline__ void mv8p_first(const f2 (&w)[4][4], const f2 (&hv)[4],
                                           f2 (&acc)[4]) {
#pragma unroll
  for (int g = 0; g < 4; ++g) {
    acc[g] = pk_mul(w[g][0], hv[0]);
#pragma unroll
    for (int k = 1; k < 4; ++k) acc[g] = pk_fma(w[g][k], hv[k], acc[g]);
  }
}
__device__ __forceinline__ void mv8p(const f2 (&w)[4][4], const f2 (&hv)[4],
                                     f2 (&acc)[4]) {
#pragma unroll
  for (int g = 0; g < 4; ++g) {
#pragma unroll
    for (int k = 0; k < 4; ++k) acc[g] = pk_fma(w[g][k], hv[k], acc[g]);
  }
}

// Collapse packed lo/hi, 2-stage DPP quad reduce (4 gates), select lane's
// gate, then finish the cross-quad (xor4) sum with DPP row_half_mirror:
// lane q pairs with 7-q. Upper-quad lanes select gate 3-(ko&3), so both
// mirror partners carry the SAME gate.
__device__ __forceinline__ float redsel(f2 (&a2)[4], bool kb0, bool kb1) {
  float a[4];
#pragma unroll
  for (int g = 0; g < 4; ++g) a[g] = a2[g].x + a2[g].y;
#pragma unroll
  for (int g = 0; g < 4; ++g) {
    a[g] = dpp_add<0xB1>(a[g]);   // quad_perm(1,0,3,2) = xor1
    a[g] = dpp_add<0x4E>(a[g]);   // quad_perm(2,3,0,1) = xor2
  }
  const float s01 = kb0 ? a[1] : a[0];
  const float s23 = kb0 ? a[3] : a[2];
  float s = kb1 ? s23 : s01;            // gate gsel (see kernel init)
  s = dpp_add<0x141>(s);                // row_half_mirror -> full K sum
  return s;
}

// Branchless activation (per-lane consts) + quad-level gate broadcast +
// c/h update. Correct in quad0; quad1 garbage is never committed (wr lane
// is in quad0, c of lanes 4..7 feeds nothing).
__device__ __forceinline__ float gate_finish(float pre, float kact, float aact,
                                             float bact, float& c) {
  const float e = fast_exp2(kact * pre);
  const float r = fast_rcp(1.0f + e);
  const float a = fmaf(aact, r, bact);
  const float vi = dpp_mov<0x00>(a);    // quad_perm(0,0,0,0): gate i
  const float vf = dpp_mov<0x55>(a);    // quad_perm(1,1,1,1): gate f
  const float vg = dpp_mov<0xAA>(a);    // quad_perm(2,2,2,2): gate g
  const float vo = dpp_mov<0xFF>(a);    // quad_perm(3,3,3,3): gate o
  c = fmaf(vf, c, vi * vg);
  const float te = fast_exp2(2.8853900817779268f * c);   // tanh(c)
  const float tr = fast_rcp(1.0f + te);
  const float t = vo * tr;
  return fmaf(-2.0f, t, vo);            // o * tanh(c)
}

// One DIAGONAL superstep: compute h0(s), h1(s-1), h2(s-2) in parallel.
// Every matvec reads parity CUR; every result writes parity NXT. Single
// barrier at the end. h0/h1 each loaded ONCE and shared by both consumers.
// act0/act1/act2 gate the c-update + h-write during pipeline fill/drain.
template <int CUR, int NXT>
__device__ __forceinline__ void lstm_step(
    float (&hb)[2][3][NB][64],
    const f2 (&whh0)[4][4], const f2 (&wih1)[4][4],
    const f2 (&whh1)[4][4], const f2 (&wih2)[4][4],
    const f2 (&whh2)[4][4],
    const float (&wi0l)[4],   // per-lane Wih0 row (gate gsel)
    float b0l, float b1l, float b2l,          // per-lane biases
    float kact, float aact, float bact,       // per-lane activation consts
    float (&c0)[NB], float (&c1)[NB], float (&c2)[NB],
    const float (&xin)[NB][4], int j, int k0,
    bool kb0, bool kb1, bool wr,
    bool act0, bool act1, bool act2) {
  f2 p0[NB][4], p1[NB][4], p2[NB][4];
  // ---- all 5 matvecs, all reading CUR; h slices loaded once ----
#pragma unroll
  for (int b = 0; b < NB; ++b) {
    f2 hv0[4], hv1[4], hv2[4];
    ld8(&hb[CUR][0][b][k0], hv0);
    ld8(&hb[CUR][1][b][k0], hv1);
    ld8(&hb[CUR][2][b][k0], hv2);
    mv8p_first(whh0, hv0, p0[b]);   // L0: h0(s-1)
    mv8p_first(wih1, hv0, p1[b]);   // L1: h0(s-1)
    mv8p      (whh1, hv1, p1[b]);   // L1: h1(s-2)
    mv8p_first(wih2, hv1, p2[b]);   // L2: h1(s-2)
    mv8p      (whh2, hv2, p2[b]);   // L2: h2(s-3)
  }
  // ---- finish all three layers (independent chains) ----
#pragma unroll
  for (int b = 0; b < NB; ++b) {
    // L0 (adds per-lane x-projection + bias)
    float s0 = redsel(p0[b], kb0, kb1);
    float d = b0l;
#pragma unroll
    for (int f2i = 0; f2i < 4; ++f2i) d = fmaf(wi0l[f2i], xin[b][f2i], d);
    float cc0 = c0[b];
    const float h0 = gate_finish(s0 + d, kact, aact, bact, cc0);
    if (act0) { c0[b] = cc0; if (wr) hb[NXT][0][b][j] = h0; }
    // L1
    float cc1 = c1[b];
    const float h1 = gate_finish(redsel(p1[b], kb0, kb1) + b1l, kact, aact, bact, cc1);
    if (act1) { c1[b] = cc1; if (wr) hb[NXT][1][b][j] = h1; }
    // L2
    float cc2 = c2[b];
    const float h2 = gate_finish(redsel(p2[b], kb0, kb1) + b2l, kact, aact, bact, cc2);
    if (act2) { c2[b] = cc2; if (wr) hb[NXT][2][b][j] = h2; }
  }
  __syncthreads();  // single barrier per superstep
}

__global__ void __launch_bounds__(NT, 2)
lstm3_kernel(const float* __restrict__ x,
             const float* __restrict__ Wih0, const float* __restrict__ Whh0,
             const float* __restrict__ bih0, const float* __restrict__ bhh0,
             const float* __restrict__ Wih1, const float* __restrict__ Whh1,
             const float* __restrict__ bih1, const float* __restrict__ bhh1,
             const float* __restrict__ Wih2, const float* __restrict__ Whh2,
             const float* __restrict__ bih2, const float* __restrict__ bhh2,
             const float* __restrict__ fcw, const float* __restrict__ fcb,
             float* __restrict__ out) {
  __shared__ float hb[2][3][NB][64];  // [parity][layer][b][k], 3 KB
  const int tid = threadIdx.x;
  const int j = tid >> 3;       // hidden unit 0..63
  const int ko = tid & 7;       // K-octant (lane bits 0..2)
  const int k0 = ko << 3;
  const int bbase = blockIdx.x * NB;
  // Gate selected by this lane after the quad reduce. Upper quad (ko&4)
  // takes the REVERSED gate order so that row_half_mirror (lane q <-> 7-q)
  // pairs identical gates for the cross-quad sum.
  const int gl = (ko & 4) ? (3 - (ko & 3)) : (ko & 3);
  const bool kb0 = (gl & 1) != 0;
  const bool kb1 = (gl & 2) != 0;
  const bool wr = (ko == 0);

  // register-resident weights: 4 gate-rows x 8-wide K slice per matrix,
  // stored as packed f2 pairs for v_pk_fma_f32
  f2 whh0[4][4], wih1[4][4], whh1[4][4], wih2[4][4], whh2[4][4];
#pragma unroll
  for (int g = 0; g < 4; ++g) {
    const int r = (g << 6) + j;   // PyTorch gate-order rows: i,f,g,o
    const int ro = (r << 6) + k0;
#define LDW(dst, srcp)                                            \
    {                                                             \
      const float4 A = *(const float4*)&(srcp)[ro];               \
      const float4 B = *(const float4*)&(srcp)[ro + 4];           \
      dst[g][0] = f2{A.x, A.y}; dst[g][1] = f2{A.z, A.w};         \
      dst[g][2] = f2{B.x, B.y}; dst[g][3] = f2{B.z, B.w};         \
    }
    LDW(whh0, Whh0)
    LDW(wih1, Wih1)
    LDW(whh1, Whh1)
    LDW(wih2, Wih2)
    LDW(whh2, Whh2)
#undef LDW
  }

  // per-lane gate-specific constants (gate = gl)
  const int rl = (gl << 6) + j;
  const float b0l = bih0[rl] + bhh0[rl];
  const float b1l = bih1[rl] + bhh1[rl];
  const float b2l = bih2[rl] + bhh2[rl];
  float wi0l[4];
  {
    const float4 w0 = *(const float4*)&Wih0[rl * 4];
    wi0l[0] = w0.x; wi0l[1] = w0.y; wi0l[2] = w0.z; wi0l[3] = w0.w;
  }
  const bool isg = (gl == 2);
  const float kact = isg ? 2.8853900817779268f : -1.4426950408889634f;
  const float aact = isg ? -2.0f : 1.0f;
  const float bact = isg ? 1.0f : 0.0f;

  float c0[NB], c1[NB], c2[NB];
#pragma unroll
  for (int b = 0; b < NB; ++b) { c0[b] = 0.f; c1[b] = 0.f; c2[b] = 0.f; }

  {  // zero both parities of h (fill steps read zeros for upper layers)
    float* p = &hb[0][0][0][0];
    for (int i = tid; i < 2 * 3 * NB * 64; i += NT) p[i] = 0.f;
  }

  // x prefetch (full 4-vector per batch elem, double-buffered)
  float xc[NB][4], xn[NB][4];
#pragma unroll
  for (int b = 0; b < NB; ++b) {
    const float4 v = *(const float4*)&x[(size_t)(bbase + b) * SS * 4];
    xc[b][0] = v.x; xc[b][1] = v.y; xc[b][2] = v.z; xc[b][3] = v.w;
  }
  __syncthreads();

  // SS+2 supersteps (2 extra for pipeline fill/drain). Superstep s:
  //   L0 computes h0(s)    -- active s < SS
  //   L1 computes h1(s-1)  -- active 1 <= s <= SS
  //   L2 computes h2(s-2)  -- active s >= 2   (last: s = SS+1)
#pragma unroll 1
  for (int t = 0; t < SS + 2; t += 2) {
    {
      const int i1 = (t + 1 < SS) ? (t + 1) : (SS - 1);
#pragma unroll
      for (int b = 0; b < NB; ++b) {
        const float4 v = *(const float4*)&x[((size_t)(bbase + b) * SS + i1) * 4];
        xn[b][0] = v.x; xn[b][1] = v.y; xn[b][2] = v.z; xn[b][3] = v.w;
      }
    }
    lstm_step<0, 1>(hb, whh0, wih1, whh1, wih2, whh2, wi0l, b0l, b1l, b2l,
                    kact, aact, bact, c0, c1, c2, xc, j, k0, kb0, kb1, wr,
                    /*act0=*/t < SS, /*act1=*/(t >= 1) && (t <= SS),
                    /*act2=*/t >= 2);
    {
      const int i2 = (t + 2 < SS) ? (t + 2) : (SS - 1);
#pragma unroll
      for (int b = 0; b < NB; ++b) {
        const float4 v = *(const float4*)&x[((size_t)(bbase + b) * SS + i2) * 4];
        xc[b][0] = v.x; xc[b][1] = v.y; xc[b][2] = v.z; xc[b][3] = v.w;
      }
    }
    lstm_step<1, 0>(hb, whh0, wih1, whh1, wih2, whh2, wi0l, b0l, b1l, b2l,
                    kact, aact, bact, c0, c1, c2, xn, j, k0, kb0, kb1, wr,
                    /*act0=*/t + 1 < SS, /*act1=*/t + 1 <= SS,
                    /*act2=*/t + 1 >= 2);
  }
  // Last superstep is s = SS+1 (odd), writes parity 0: h2(SS-1) in hb[0][2].
  __syncthreads();

  // fc: out[b][o] = fc_b[o] + sum_j fc_w[o][j] * h2_last[b][j]
  if (tid < NB * 2) {
    const int b = tid >> 1, o = tid & 1;
    float s = fcb[o];
#pragma unroll
    for (int jj = 0; jj < 64; ++jj)
      s = fmaf(fcw[o * 64 + jj], hb[0][2][b][jj], s);
    out[(bbase + b) * 2 + o] = s;
  }
}

extern "C" void kernel_launch(void* const* d_in, const int* in_sizes, int n_in,
                              void* d_out, int out_size, void* d_ws, size_t ws_size,
                              hipStream_t stream) {
  const float* x    = (const float*)d_in[0];
  const float* Wih0 = (const float*)d_in[1];
  const float* Whh0 = (const float*)d_in[2];
  const float* bih0 = (const float*)d_in[3];
  const float* bhh0 = (const float*)d_in[4];
  const float* Wih1 = (const float*)d_in[5];
  const float* Whh1 = (const float*)d_in[6];
  const float* bih1 = (const float*)d_in[7];
  const float* bhh1 = (const float*)d_in[8];
  const float* Wih2 = (const float*)d_in[9];
  const float* Whh2 = (const float*)d_in[10];
  const float* bih2 = (const float*)d_in[11];
  const float* bhh2 = (const float*)d_in[12];
  const float* fcw  = (const float*)d_in[13];
  const float* fcb  = (const float*)d_in[14];
  float* out = (float*)d_out;

  lstm3_kernel<<<dim3(BATCH / NB), dim3(NT), 0, stream>>>(
      x, Wih0, Whh0, bih0, bhh0, Wih1, Whh1, bih1, bhh1,
      Wih2, Whh2, bih2, bhh2, fcw, fcb, out);
}

// Round 6
// 3093.165 us; speedup vs baseline: 6.2868x; 1.1213x over previous
//
#include <hip/hip_runtime.h>

#define SS 2048
#define BATCH 512
#define NB 2          // batch elements per block
#define NT 512        // threads per block: 64 j * 8 ko

typedef float f2 __attribute__((ext_vector_type(2)));

// ---------- fast fp32 helpers ----------
__device__ __forceinline__ float fast_rcp(float a) { return __builtin_amdgcn_rcpf(a); }
__device__ __forceinline__ float fast_exp2(float a) { return __builtin_amdgcn_exp2f(a); }

// ---------- packed fp32 via native vector ops (-> v_pk_fma_f32) ----------
__device__ __forceinline__ f2 pk_fma(f2 a, f2 b, f2 c) {
  return __builtin_elementwise_fma(a, b, c);
}
__device__ __forceinline__ f2 pk_mul(f2 a, f2 b) { return a * b; }

// ---------- DPP add / mov ----------
template <int CTRL>
__device__ __forceinline__ float dpp_add(float v) {
  const int sh = __builtin_amdgcn_update_dpp(0, __float_as_int(v), CTRL, 0xf, 0xf, true);
  return v + __int_as_float(sh);
}
template <int CTRL>
__device__ __forceinline__ float dpp_mov(float v) {
  return __int_as_float(__builtin_amdgcn_update_dpp(0, __float_as_int(v), CTRL, 0xf, 0xf, true));
}

// ---------- LDS-only barrier (skip the vmcnt drain of __syncthreads) ----------
// Cross-thread communication in the main loop is exclusively via LDS, so
// lgkmcnt(0)+s_barrier is sufficient; global x-prefetch loads stay in flight.
__device__ __forceinline__ void lds_barrier() {
  asm volatile("s_waitcnt lgkmcnt(0)\n\ts_barrier" ::: "memory");
}

// ---------- load this thread's 8-wide h slice as 4 packed pairs ----------
__device__ __forceinline__ void ld8(const float* p, f2 (&hv)[4]) {
  const float4 A = *(const float4*)p;
  const float4 B = *(const float4*)(p + 4);
  hv[0] = f2{A.x, A.y}; hv[1] = f2{A.z, A.w};
  hv[2] = f2{B.x, B.y}; hv[3] = f2{B.z, B.w};
}

// ---------- packed matvec over the 8-wide K slice (4 gates) ----------
__device__ __forceinline__ void mv8p_first(const f2 (&w)[4][4], const f2 (&hv)[4],
                                           f2 (&acc)[4]) {
#pragma unroll
  for (int g = 0; g < 4; ++g) {
    acc[g] = pk_mul(w[g][0], hv[0]);
#pragma unroll
    for (int k = 1; k < 4; ++k) acc[g] = pk_fma(w[g][k], hv[k], acc[g]);
  }
}
__device__ __forceinline__ void mv8p(const f2 (&w)[4][4], const f2 (&hv)[4],
                                     f2 (&acc)[4]) {
#pragma unroll
  for (int g = 0; g < 4; ++g) {
#pragma unroll
    for (int k = 0; k < 4; ++k) acc[g] = pk_fma(w[g][k], hv[k], acc[g]);
  }
}

// Dual-batch reduce+select: collapse packed lo/hi and quad-reduce (xor1,xor2)
// for BOTH batch elements, select this lane's gate (gl; reversed order in
// quad1), then ONE mirror exchange ships the other quad's partial for this
// lane's ASSIGNED batch (quad0 -> b0, quad1 -> b1): quad0 sends its b1
// partial and receives its b0 complement, vice versa for quad1. The final
// add (own + recv) pairs the same two addends as before -> bitwise equal.
__device__ __forceinline__ float redsel2(const f2 (&A)[4], const f2 (&B)[4],
                                         bool kb0, bool kb1, bool bsel) {
  float a[4], b[4];
#pragma unroll
  for (int g = 0; g < 4; ++g) { a[g] = A[g].x + A[g].y; b[g] = B[g].x + B[g].y; }
#pragma unroll
  for (int g = 0; g < 4; ++g) {
    a[g] = dpp_add<0xB1>(a[g]);   // quad_perm(1,0,3,2) = xor1
    a[g] = dpp_add<0x4E>(a[g]);   // quad_perm(2,3,0,1) = xor2
    b[g] = dpp_add<0xB1>(b[g]);
    b[g] = dpp_add<0x4E>(b[g]);
  }
  const float t0 = kb1 ? (kb0 ? a[3] : a[2]) : (kb0 ? a[1] : a[0]);  // b0, gate gl
  const float t1 = kb1 ? (kb0 ? b[3] : b[2]) : (kb0 ? b[1] : b[0]);  // b1, gate gl
  const float send = bsel ? t0 : t1;
  const float recv = dpp_mov<0x141>(send);   // row_half_mirror: lane q <-> 7-q
  const float own  = bsel ? t1 : t0;
  return own + recv;
}

// Single-batch finish per lane (lane's batch = its quad). Quad-local gate
// positions: quad0 (i,f,g,o) at (0,1,2,3); quad1 reversed (o,g,f,i), i.e.
// i@3, f@2, g@1, o@0 -- handled by bsel-selected operands. All surviving
// values are operand-identical to the old two-pass code (muls/adds commute
// bitwise), so results are unchanged.
__device__ __forceinline__ float gate_finish2(float pre, float kact, float aact,
                                              float bact, float& c, bool bsel) {
  const float e = fast_exp2(kact * pre);
  const float r = fast_rcp(1.0f + e);
  const float a = fmaf(aact, r, bact);
  const float u0 = dpp_mov<0x00>(a);    // quad_perm(0,0,0,0)
  const float u1 = dpp_mov<0x55>(a);    // quad_perm(1,1,1,1)
  const float u2 = dpp_mov<0xAA>(a);    // quad_perm(2,2,2,2)
  const float u3 = dpp_mov<0xFF>(a);    // quad_perm(3,3,3,3)
  const float prod = bsel ? (u3 * u1) : (u0 * u2);   // a_i * a_g
  const float vf   = bsel ? u2 : u1;                 // a_f
  const float vo   = bsel ? u0 : u3;                 // a_o
  c = fmaf(vf, c, prod);
  const float te = fast_exp2(2.8853900817779268f * c);   // tanh(c)
  const float tr = fast_rcp(1.0f + te);
  const float t = vo * tr;
  return fmaf(-2.0f, t, vo);            // o * tanh(c)
}

// One DIAGONAL superstep: compute h0(s), h1(s-1), h2(s-2). All matvecs read
// parity CUR; results write parity NXT; single LDS barrier at the end.
// Finish phase is batch-split across quads (quad0 -> b0, quad1 -> b1).
template <int CUR, int NXT>
__device__ __forceinline__ void lstm_step(
    float (&hb)[2][3][NB][64],
    const f2 (&whh0)[4][4], const f2 (&wih1)[4][4],
    const f2 (&whh1)[4][4], const f2 (&wih2)[4][4],
    const f2 (&whh2)[4][4],
    const float (&wi0l)[4],   // per-lane Wih0 row (gate gl)
    float b0l, float b1l, float b2l,          // per-lane biases
    float kact, float aact, float bact,       // per-lane activation consts
    float& c0, float& c1, float& c2,          // lane's batch c-state
    const float (&xin)[NB][4], int j, int k0, int bi,
    bool kb0, bool kb1, bool bsel, bool wq,
    bool act0, bool act1, bool act2) {
  f2 p0[NB][4], p1[NB][4], p2[NB][4];
  // ---- all 5 matvecs for BOTH batches, reading CUR; h loaded once ----
#pragma unroll
  for (int b = 0; b < NB; ++b) {
    f2 hv0[4], hv1[4], hv2[4];
    ld8(&hb[CUR][0][b][k0], hv0);
    ld8(&hb[CUR][1][b][k0], hv1);
    ld8(&hb[CUR][2][b][k0], hv2);
    mv8p_first(whh0, hv0, p0[b]);   // L0: h0(s-1)
    mv8p_first(wih1, hv0, p1[b]);   // L1: h0(s-1)
    mv8p      (whh1, hv1, p1[b]);   // L1: h1(s-2)
    mv8p_first(wih2, hv1, p2[b]);   // L2: h1(s-2)
    mv8p      (whh2, hv2, p2[b]);   // L2: h2(s-3)
  }
  // ---- finish: one chain per layer per lane (lane's batch) ----
  // L0 (x-projection for the lane's batch + bias)
  {
    const float s = redsel2(p0[0], p0[1], kb0, kb1, bsel);
    float d = b0l;
#pragma unroll
    for (int f = 0; f < 4; ++f)
      d = fmaf(wi0l[f], bsel ? xin[1][f] : xin[0][f], d);
    float cc = c0;
    const float h = gate_finish2(s + d, kact, aact, bact, cc, bsel);
    if (act0) { c0 = cc; if (wq) hb[NXT][0][bi][j] = h; }
  }
  // L1
  {
    const float s = redsel2(p1[0], p1[1], kb0, kb1, bsel);
    float cc = c1;
    const float h = gate_finish2(s + b1l, kact, aact, bact, cc, bsel);
    if (act1) { c1 = cc; if (wq) hb[NXT][1][bi][j] = h; }
  }
  // L2
  {
    const float s = redsel2(p2[0], p2[1], kb0, kb1, bsel);
    float cc = c2;
    const float h = gate_finish2(s + b2l, kact, aact, bact, cc, bsel);
    if (act2) { c2 = cc; if (wq) hb[NXT][2][bi][j] = h; }
  }
  lds_barrier();  // single barrier per superstep (LDS-only)
}

__global__ void __launch_bounds__(NT, 2)
lstm3_kernel(const float* __restrict__ x,
             const float* __restrict__ Wih0, const float* __restrict__ Whh0,
             const float* __restrict__ bih0, const float* __restrict__ bhh0,
             const float* __restrict__ Wih1, const float* __restrict__ Whh1,
             const float* __restrict__ bih1, const float* __restrict__ bhh1,
             const float* __restrict__ Wih2, const float* __restrict__ Whh2,
             const float* __restrict__ bih2, const float* __restrict__ bhh2,
             const float* __restrict__ fcw, const float* __restrict__ fcb,
             float* __restrict__ out) {
  __shared__ float hb[2][3][NB][64];  // [parity][layer][b][k], 3 KB
  const int tid = threadIdx.x;
  const int j = tid >> 3;       // hidden unit 0..63
  const int ko = tid & 7;       // K-octant (lane bits 0..2)
  const int k0 = ko << 3;
  const int bbase = blockIdx.x * NB;
  // Gate selected by this lane after the quad reduce. Upper quad (ko&4)
  // takes the REVERSED gate order so that row_half_mirror (lane q <-> 7-q)
  // pairs identical gates for the cross-quad sum.
  const int gl = (ko & 4) ? (3 - (ko & 3)) : (ko & 3);
  const bool kb0 = (gl & 1) != 0;
  const bool kb1 = (gl & 2) != 0;
  const int  bi   = (ko >> 2) & 1;    // lane's batch element
  const bool bsel = bi != 0;
  const bool wq   = (ko & 3) == 0;    // one writer lane per quad

  // register-resident weights: 4 gate-rows x 8-wide K slice per matrix,
  // stored as packed f2 pairs for v_pk_fma_f32
  f2 whh0[4][4], wih1[4][4], whh1[4][4], wih2[4][4], whh2[4][4];
#pragma unroll
  for (int g = 0; g < 4; ++g) {
    const int r = (g << 6) + j;   // PyTorch gate-order rows: i,f,g,o
    const int ro = (r << 6) + k0;
#define LDW(dst, srcp)                                            \
    {                                                             \
      const float4 A = *(const float4*)&(srcp)[ro];               \
      const float4 B = *(const float4*)&(srcp)[ro + 4];           \
      dst[g][0] = f2{A.x, A.y}; dst[g][1] = f2{A.z, A.w};         \
      dst[g][2] = f2{B.x, B.y}; dst[g][3] = f2{B.z, B.w};         \
    }
    LDW(whh0, Whh0)
    LDW(wih1, Wih1)
    LDW(whh1, Whh1)
    LDW(wih2, Wih2)
    LDW(whh2, Whh2)
#undef LDW
  }

  // per-lane gate-specific constants (gate = gl)
  const int rl = (gl << 6) + j;
  const float b0l = bih0[rl] + bhh0[rl];
  const float b1l = bih1[rl] + bhh1[rl];
  const float b2l = bih2[rl] + bhh2[rl];
  float wi0l[4];
  {
    const float4 w0 = *(const float4*)&Wih0[rl * 4];
    wi0l[0] = w0.x; wi0l[1] = w0.y; wi0l[2] = w0.z; wi0l[3] = w0.w;
  }
  const bool isg = (gl == 2);
  const float kact = isg ? 2.8853900817779268f : -1.4426950408889634f;
  const float aact = isg ? -2.0f : 1.0f;
  const float bact = isg ? 1.0f : 0.0f;

  float c0 = 0.f, c1 = 0.f, c2 = 0.f;   // c-state for the lane's batch

  {  // zero both parities of h (fill steps read zeros for upper layers)
    float* p = &hb[0][0][0][0];
    for (int i = tid; i < 2 * 3 * NB * 64; i += NT) p[i] = 0.f;
  }

  // x prefetch (full 4-vector per batch elem, double-buffered)
  float xc[NB][4], xn[NB][4];
#pragma unroll
  for (int b = 0; b < NB; ++b) {
    const float4 v = *(const float4*)&x[(size_t)(bbase + b) * SS * 4];
    xc[b][0] = v.x; xc[b][1] = v.y; xc[b][2] = v.z; xc[b][3] = v.w;
  }
  __syncthreads();

  // SS+2 supersteps (2 extra for pipeline fill/drain). Superstep s:
  //   L0 computes h0(s)    -- active s < SS
  //   L1 computes h1(s-1)  -- active 1 <= s <= SS
  //   L2 computes h2(s-2)  -- active s >= 2   (last: s = SS+1)
#pragma unroll 1
  for (int t = 0; t < SS + 2; t += 2) {
    {
      const int i1 = (t + 1 < SS) ? (t + 1) : (SS - 1);
#pragma unroll
      for (int b = 0; b < NB; ++b) {
        const float4 v = *(const float4*)&x[((size_t)(bbase + b) * SS + i1) * 4];
        xn[b][0] = v.x; xn[b][1] = v.y; xn[b][2] = v.z; xn[b][3] = v.w;
      }
    }
    lstm_step<0, 1>(hb, whh0, wih1, whh1, wih2, whh2, wi0l, b0l, b1l, b2l,
                    kact, aact, bact, c0, c1, c2, xc, j, k0, bi,
                    kb0, kb1, bsel, wq,
                    /*act0=*/t < SS, /*act1=*/(t >= 1) && (t <= SS),
                    /*act2=*/t >= 2);
    {
      const int i2 = (t + 2 < SS) ? (t + 2) : (SS - 1);
#pragma unroll
      for (int b = 0; b < NB; ++b) {
        const float4 v = *(const float4*)&x[((size_t)(bbase + b) * SS + i2) * 4];
        xc[b][0] = v.x; xc[b][1] = v.y; xc[b][2] = v.z; xc[b][3] = v.w;
      }
    }
    lstm_step<1, 0>(hb, whh0, wih1, whh1, wih2, whh2, wi0l, b0l, b1l, b2l,
                    kact, aact, bact, c0, c1, c2, xn, j, k0, bi,
                    kb0, kb1, bsel, wq,
                    /*act0=*/t + 1 < SS, /*act1=*/t + 1 <= SS,
                    /*act2=*/t + 1 >= 2);
  }
  // Last superstep is s = SS+1 (odd), writes parity 0: h2(SS-1) in hb[0][2].
  __syncthreads();

  // fc: out[b][o] = fc_b[o] + sum_j fc_w[o][j] * h2_last[b][j]
  if (tid < NB * 2) {
    const int b = tid >> 1, o = tid & 1;
    float s = fcb[o];
#pragma unroll
    for (int jj = 0; jj < 64; ++jj)
      s = fmaf(fcw[o * 64 + jj], hb[0][2][b][jj], s);
    out[(bbase + b) * 2 + o] = s;
  }
}

extern "C" void kernel_launch(void* const* d_in, const int* in_sizes, int n_in,
                              void* d_out, int out_size, void* d_ws, size_t ws_size,
                              hipStream_t stream) {
  const float* x    = (const float*)d_in[0];
  const float* Wih0 = (const float*)d_in[1];
  const float* Whh0 = (const float*)d_in[2];
  const float* bih0 = (const float*)d_in[3];
  const float* bhh0 = (const float*)d_in[4];
  const float* Wih1 = (const float*)d_in[5];
  const float* Whh1 = (const float*)d_in[6];
  const float* bih1 = (const float*)d_in[7];
  const float* bhh1 = (const float*)d_in[8];
  const float* Wih2 = (const float*)d_in[9];
  const float* Whh2 = (const float*)d_in[10];
  const float* bih2 = (const float*)d_in[11];
  const float* bhh2 = (const float*)d_in[12];
  const float* fcw  = (const float*)d_in[13];
  const float* fcb  = (const float*)d_in[14];
  float* out = (float*)d_out;

  lstm3_kernel<<<dim3(BATCH / NB), dim3(NT), 0, stream>>>(
      x, Wih0, Whh0, bih0, bhh0, Wih1, Whh1, bih1, bhh1,
      Wih2, Whh2, bih2, bhh2, fcw, fcb, out);
}

// Round 7
// 2864.353 us; speedup vs baseline: 6.7890x; 1.0799x over previous
//
#include <hip/hip_runtime.h>

#define SS 2048
#define BATCH 512
#define NB 2          // batch elements per block
#define NT 512        // threads per block: 64 j * 8 ko
#define HS 72         // h-row stride in floats: 288B keeps float4 alignment,
                      // bank offset 8 between batches -> write banks disjoint

typedef float f2 __attribute__((ext_vector_type(2)));

// ---------- fast fp32 helpers ----------
__device__ __forceinline__ float fast_rcp(float a) { return __builtin_amdgcn_rcpf(a); }
__device__ __forceinline__ float fast_exp2(float a) { return __builtin_amdgcn_exp2f(a); }

// ---------- packed fp32 via native vector ops (-> v_pk_fma_f32) ----------
__device__ __forceinline__ f2 pk_fma(f2 a, f2 b, f2 c) {
  return __builtin_elementwise_fma(a, b, c);
}
__device__ __forceinline__ f2 pk_mul(f2 a, f2 b) { return a * b; }

// ---------- DPP helpers ----------
// dpp_add: update_dpp(old=0) feeding an add -> GCNDPPCombine fuses to a
// single v_add_f32_dpp (0 is the add identity). Keep builtin form so the
// compiler handles DPP hazards.
template <int CTRL>
__device__ __forceinline__ float dpp_add(float v) {
  const int sh = __builtin_amdgcn_update_dpp(0, __float_as_int(v), CTRL, 0xf, 0xf, true);
  return v + __int_as_float(sh);
}
// mirror_add: o + row_half_mirror(s), same fusable pattern.
__device__ __forceinline__ float mirror_add(float s, float o) {
  const int sh = __builtin_amdgcn_update_dpp(0, __float_as_int(s), 0x141, 0xf, 0xf, true);
  return o + __int_as_float(sh);
}
// dpp_mov: mov_dpp has NO tied-old operand -> single v_mov_b32_dpp (the
// update_dpp form costs an extra v_mov dst,0 per use).
template <int CTRL>
__device__ __forceinline__ float dpp_mov(float v) {
  return __int_as_float(__builtin_amdgcn_mov_dpp(__float_as_int(v), CTRL, 0xf, 0xf, true));
}

// ---------- LDS-only barrier (skip the vmcnt drain of __syncthreads) ----------
__device__ __forceinline__ void lds_barrier() {
  asm volatile("s_waitcnt lgkmcnt(0)\n\ts_barrier" ::: "memory");
}

// ---------- load this thread's 8-wide h slice as 4 packed pairs ----------
__device__ __forceinline__ void ld8(const float* p, f2 (&hv)[4]) {
  const float4 A = *(const float4*)p;
  const float4 B = *(const float4*)(p + 4);
  hv[0] = f2{A.x, A.y}; hv[1] = f2{A.z, A.w};
  hv[2] = f2{B.x, B.y}; hv[3] = f2{B.z, B.w};
}

// ---------- packed matvec over the 8-wide K slice (4 gates) ----------
__device__ __forceinline__ void mv8p_first(const f2 (&w)[4][4], const f2 (&hv)[4],
                                           f2 (&acc)[4]) {
#pragma unroll
  for (int g = 0; g < 4; ++g) {
    acc[g] = pk_mul(w[g][0], hv[0]);
#pragma unroll
    for (int k = 1; k < 4; ++k) acc[g] = pk_fma(w[g][k], hv[k], acc[g]);
  }
}
__device__ __forceinline__ void mv8p(const f2 (&w)[4][4], const f2 (&hv)[4],
                                     f2 (&acc)[4]) {
#pragma unroll
  for (int g = 0; g < 4; ++g) {
#pragma unroll
    for (int k = 0; k < 4; ++k) acc[g] = pk_fma(w[g][k], hv[k], acc[g]);
  }
}

// Dual-batch reduce+select (see round-6 comment): quad-reduce both batches,
// select lane's gate, one mirror exchange ships the other quad's partial for
// the lane's assigned batch. own + dpp(send) is bitwise the old pair-sum.
__device__ __forceinline__ float redsel2(const f2 (&A)[4], const f2 (&B)[4],
                                         bool kb0, bool kb1, bool bsel) {
  float a[4], b[4];
#pragma unroll
  for (int g = 0; g < 4; ++g) { a[g] = A[g].x + A[g].y; b[g] = B[g].x + B[g].y; }
#pragma unroll
  for (int g = 0; g < 4; ++g) {
    a[g] = dpp_add<0xB1>(a[g]);   // quad_perm(1,0,3,2) = xor1
    a[g] = dpp_add<0x4E>(a[g]);   // quad_perm(2,3,0,1) = xor2
    b[g] = dpp_add<0xB1>(b[g]);
    b[g] = dpp_add<0x4E>(b[g]);
  }
  const float t0 = kb1 ? (kb0 ? a[3] : a[2]) : (kb0 ? a[1] : a[0]);  // b0, gate gl
  const float t1 = kb1 ? (kb0 ? b[3] : b[2]) : (kb0 ? b[1] : b[0]);  // b1, gate gl
  const float send = bsel ? t0 : t1;
  const float own  = bsel ? t1 : t0;
  return mirror_add(send, own);
}

// Single-batch finish per lane (lane's batch = its quad). Quad0 gates
// (i,f,g,o) at lanes (0,1,2,3); quad1 reversed -> bsel-selected operands.
__device__ __forceinline__ float gate_finish2(float pre, float kact, float aact,
                                              float bact, float& c, bool bsel) {
  const float e = fast_exp2(kact * pre);
  const float r = fast_rcp(1.0f + e);
  const float a = fmaf(aact, r, bact);
  const float u0 = dpp_mov<0x00>(a);    // quad_perm(0,0,0,0)
  const float u1 = dpp_mov<0x55>(a);    // quad_perm(1,1,1,1)
  const float u2 = dpp_mov<0xAA>(a);    // quad_perm(2,2,2,2)
  const float u3 = dpp_mov<0xFF>(a);    // quad_perm(3,3,3,3)
  const float prod = bsel ? (u3 * u1) : (u0 * u2);   // a_i * a_g
  const float vf   = bsel ? u2 : u1;                 // a_f
  const float vo   = bsel ? u0 : u3;                 // a_o
  c = fmaf(vf, c, prod);
  const float te = fast_exp2(2.8853900817779268f * c);   // tanh(c)
  const float tr = fast_rcp(1.0f + te);
  const float t = vo * tr;
  return fmaf(-2.0f, t, vo);            // o * tanh(c)
}

// One DIAGONAL superstep: h0(s), h1(s-1), h2(s-2). All matvecs read parity
// CUR; results write parity NXT; single LDS barrier at the end. A0/A1/A2 are
// compile-time activity flags (fill/drain peeled outside the steady loop).
template <int CUR, int NXT, bool A0, bool A1, bool A2>
__device__ __forceinline__ void lstm_step(
    float (&hb)[2][3][NB][HS],
    const f2 (&whh0)[4][4], const f2 (&wih1)[4][4],
    const f2 (&whh1)[4][4], const f2 (&wih2)[4][4],
    const f2 (&whh2)[4][4],
    const float (&wi0l)[4],   // per-lane Wih0 row (gate gl)
    float b0l, float b1l, float b2l,
    float kact, float aact, float bact,
    float& c0, float& c1, float& c2,
    const float (&xin)[4],    // lane's batch x(s)
    int j, int k0, int bi,
    bool kb0, bool kb1, bool bsel, bool wq) {
  f2 p0[NB][4], p1[NB][4], p2[NB][4];
  // ---- all 5 matvecs for BOTH batches, reading CUR; h loaded once ----
#pragma unroll
  for (int b = 0; b < NB; ++b) {
    f2 hv0[4], hv1[4], hv2[4];
    ld8(&hb[CUR][0][b][k0], hv0);
    ld8(&hb[CUR][1][b][k0], hv1);
    ld8(&hb[CUR][2][b][k0], hv2);
    mv8p_first(whh0, hv0, p0[b]);   // L0: h0(s-1)
    mv8p_first(wih1, hv0, p1[b]);   // L1: h0(s-1)
    mv8p      (whh1, hv1, p1[b]);   // L1: h1(s-2)
    mv8p_first(wih2, hv1, p2[b]);   // L2: h1(s-2)
    mv8p      (whh2, hv2, p2[b]);   // L2: h2(s-3)
  }
  // ---- finish: one chain per layer per lane (lane's batch) ----
  if (A0) {
    const float s = redsel2(p0[0], p0[1], kb0, kb1, bsel);
    float d = b0l;
#pragma unroll
    for (int f = 0; f < 4; ++f) d = fmaf(wi0l[f], xin[f], d);
    float cc = c0;
    const float h = gate_finish2(s + d, kact, aact, bact, cc, bsel);
    c0 = cc;
    if (wq) hb[NXT][0][bi][j] = h;
  }
  if (A1) {
    const float s = redsel2(p1[0], p1[1], kb0, kb1, bsel);
    float cc = c1;
    const float h = gate_finish2(s + b1l, kact, aact, bact, cc, bsel);
    c1 = cc;
    if (wq) hb[NXT][1][bi][j] = h;
  }
  if (A2) {
    const float s = redsel2(p2[0], p2[1], kb0, kb1, bsel);
    float cc = c2;
    const float h = gate_finish2(s + b2l, kact, aact, bact, cc, bsel);
    c2 = cc;
    if (wq) hb[NXT][2][bi][j] = h;
  }
  lds_barrier();  // single barrier per superstep (LDS-only)
}

__global__ void __launch_bounds__(NT, 2)
lstm3_kernel(const float* __restrict__ x,
             const float* __restrict__ Wih0, const float* __restrict__ Whh0,
             const float* __restrict__ bih0, const float* __restrict__ bhh0,
             const float* __restrict__ Wih1, const float* __restrict__ Whh1,
             const float* __restrict__ bih1, const float* __restrict__ bhh1,
             const float* __restrict__ Wih2, const float* __restrict__ Whh2,
             const float* __restrict__ bih2, const float* __restrict__ bhh2,
             const float* __restrict__ fcw, const float* __restrict__ fcb,
             float* __restrict__ out) {
  __shared__ __align__(16) float hb[2][3][NB][HS];  // [parity][layer][b][k]
  const int tid = threadIdx.x;
  const int j = tid >> 3;       // hidden unit 0..63
  const int ko = tid & 7;       // K-octant (lane bits 0..2)
  const int k0 = ko << 3;
  const int bbase = blockIdx.x * NB;
  // Lane's gate after the quad reduce (quad1 reversed for the mirror pairing)
  const int gl = (ko & 4) ? (3 - (ko & 3)) : (ko & 3);
  const bool kb0 = (gl & 1) != 0;
  const bool kb1 = (gl & 2) != 0;
  const int  bi   = (ko >> 2) & 1;    // lane's batch element
  const bool bsel = bi != 0;
  const bool wq   = (ko & 3) == 0;    // one writer lane per quad

  // register-resident weights: 4 gate-rows x 8-wide K slice per matrix
  f2 whh0[4][4], wih1[4][4], whh1[4][4], wih2[4][4], whh2[4][4];
#pragma unroll
  for (int g = 0; g < 4; ++g) {
    const int r = (g << 6) + j;   // PyTorch gate-order rows: i,f,g,o
    const int ro = (r << 6) + k0;
#define LDW(dst, srcp)                                            \
    {                                                             \
      const float4 A = *(const float4*)&(srcp)[ro];               \
      const float4 B = *(const float4*)&(srcp)[ro + 4];           \
      dst[g][0] = f2{A.x, A.y}; dst[g][1] = f2{A.z, A.w};         \
      dst[g][2] = f2{B.x, B.y}; dst[g][3] = f2{B.z, B.w};         \
    }
    LDW(whh0, Whh0)
    LDW(wih1, Wih1)
    LDW(whh1, Whh1)
    LDW(wih2, Wih2)
    LDW(whh2, Whh2)
#undef LDW
  }

  // per-lane gate-specific constants (gate = gl)
  const int rl = (gl << 6) + j;
  const float b0l = bih0[rl] + bhh0[rl];
  const float b1l = bih1[rl] + bhh1[rl];
  const float b2l = bih2[rl] + bhh2[rl];
  float wi0l[4];
  {
    const float4 w0 = *(const float4*)&Wih0[rl * 4];
    wi0l[0] = w0.x; wi0l[1] = w0.y; wi0l[2] = w0.z; wi0l[3] = w0.w;
  }
  const bool isg = (gl == 2);
  const float kact = isg ? 2.8853900817779268f : -1.4426950408889634f;
  const float aact = isg ? -2.0f : 1.0f;
  const float bact = isg ? 1.0f : 0.0f;

  float c0 = 0.f, c1 = 0.f, c2 = 0.f;   // c-state for the lane's batch

  {  // zero both parities of h (fill steps read zeros for upper layers)
    float* p = &hb[0][0][0][0];
    for (int i = tid; i < 2 * 3 * NB * HS; i += NT) p[i] = 0.f;
  }

  // x prefetch: lane's batch only, double-buffered
  const float* xlane = &x[(size_t)(bbase + bi) * SS * 4];
  float xc[4], xn[4];
  {
    const float4 v = *(const float4*)xlane;
    xc[0] = v.x; xc[1] = v.y; xc[2] = v.z; xc[3] = v.w;
  }
  __syncthreads();

#define LOADX(dst, idx)                                           \
  {                                                               \
    const float4 v = *(const float4*)&xlane[(idx) * 4];           \
    dst[0] = v.x; dst[1] = v.y; dst[2] = v.z; dst[3] = v.w;       \
  }
#define STEP(CUR, NXT, A0, A1, A2, xv)                                       \
  lstm_step<CUR, NXT, A0, A1, A2>(hb, whh0, wih1, whh1, wih2, whh2, wi0l,    \
                                  b0l, b1l, b2l, kact, aact, bact,           \
                                  c0, c1, c2, xv, j, k0, bi, kb0, kb1,       \
                                  bsel, wq)

  // Supersteps s=0..SS+1 (diagonal pipeline; 2 fill + 2 drain peeled).
  // s=0:
  LOADX(xn, 1)
  STEP(0, 1, true, false, false, xc);
  LOADX(xc, 2)
  // s=1:
  STEP(1, 0, true, true, false, xn);
  // steady: s=2..SS-1 (all layers active), 1023 iterations
#pragma unroll 1
  for (int t = 2; t < SS; t += 2) {
    LOADX(xn, t + 1)
    STEP(0, 1, true, true, true, xc);
    const int tp = (t + 2 < SS) ? (t + 2) : (SS - 1);
    LOADX(xc, tp)
    STEP(1, 0, true, true, true, xn);
  }
  // s=SS (L1 last + L2):
  STEP(0, 1, false, true, true, xc);
  // s=SS+1 (L2 last): writes h2(SS-1) into parity 0
  STEP(1, 0, false, false, true, xn);
  __syncthreads();

  // fc: out[b][o] = fc_b[o] + sum_j fc_w[o][j] * h2_last[b][j]
  if (tid < NB * 2) {
    const int b = tid >> 1, o = tid & 1;
    float s = fcb[o];
#pragma unroll
    for (int jj = 0; jj < 64; ++jj)
      s = fmaf(fcw[o * 64 + jj], hb[0][2][b][jj], s);
    out[(bbase + b) * 2 + o] = s;
  }
#undef LOADX
#undef STEP
}

extern "C" void kernel_launch(void* const* d_in, const int* in_sizes, int n_in,
                              void* d_out, int out_size, void* d_ws, size_t ws_size,
                              hipStream_t stream) {
  const float* x    = (const float*)d_in[0];
  const float* Wih0 = (const float*)d_in[1];
  const float* Whh0 = (const float*)d_in[2];
  const float* bih0 = (const float*)d_in[3];
  const float* bhh0 = (const float*)d_in[4];
  const float* Wih1 = (const float*)d_in[5];
  const float* Whh1 = (const float*)d_in[6];
  const float* bih1 = (const float*)d_in[7];
  const float* bhh1 = (const float*)d_in[8];
  const float* Wih2 = (const float*)d_in[9];
  const float* Whh2 = (const float*)d_in[10];
  const float* bih2 = (const float*)d_in[11];
  const float* bhh2 = (const float*)d_in[12];
  const float* fcw  = (const float*)d_in[13];
  const float* fcb  = (const float*)d_in[14];
  float* out = (float*)d_out;

  lstm3_kernel<<<dim3(BATCH / NB), dim3(NT), 0, stream>>>(
      x, Wih0, Whh0, bih0, bhh0, Wih1, Whh1, bih1, bhh1,
      Wih2, Whh2, bih2, bhh2, fcw, fcb, out);
}

// Round 8
// 2852.819 us; speedup vs baseline: 6.8165x; 1.0040x over previous
//
#include <hip/hip_runtime.h>

#define SS 2048
#define BATCH 512
#define NB 2          // batch elements per block
#define NT 512        // threads per block: 64 j * 8 ko
#define HS 72         // h-row stride in floats: 288B keeps float4 alignment,
                      // bank offset 8 between batches -> write banks disjoint

typedef float f2 __attribute__((ext_vector_type(2)));

// ---------- fast fp32 helpers ----------
__device__ __forceinline__ float fast_rcp(float a) { return __builtin_amdgcn_rcpf(a); }
__device__ __forceinline__ float fast_exp2(float a) { return __builtin_amdgcn_exp2f(a); }

// ---------- packed fp32 via native vector ops (-> v_pk_fma_f32) ----------
__device__ __forceinline__ f2 pk_fma(f2 a, f2 b, f2 c) {
  return __builtin_elementwise_fma(a, b, c);
}
__device__ __forceinline__ f2 pk_mul(f2 a, f2 b) { return a * b; }

// ---------- DPP helpers ----------
template <int CTRL>
__device__ __forceinline__ float dpp_add(float v) {
  const int sh = __builtin_amdgcn_update_dpp(0, __float_as_int(v), CTRL, 0xf, 0xf, true);
  return v + __int_as_float(sh);
}
__device__ __forceinline__ float mirror_add(float s, float o) {
  const int sh = __builtin_amdgcn_update_dpp(0, __float_as_int(s), 0x141, 0xf, 0xf, true);
  return o + __int_as_float(sh);
}
template <int CTRL>
__device__ __forceinline__ float dpp_mov(float v) {
  return __int_as_float(__builtin_amdgcn_mov_dpp(__float_as_int(v), CTRL, 0xf, 0xf, true));
}

// ---------- LDS-only barrier (skip the vmcnt drain of __syncthreads) ----------
__device__ __forceinline__ void lds_barrier() {
  asm volatile("s_waitcnt lgkmcnt(0)\n\ts_barrier" ::: "memory");
}

// ---------- load one layer's 8-wide h slice for BOTH batches ----------
__device__ __forceinline__ void ld8x2(const float* p0, const float* p1,
                                      f2 (&hv)[2][4]) {
  const float4 A0 = *(const float4*)p0;
  const float4 B0 = *(const float4*)(p0 + 4);
  const float4 A1 = *(const float4*)p1;
  const float4 B1 = *(const float4*)(p1 + 4);
  hv[0][0] = f2{A0.x, A0.y}; hv[0][1] = f2{A0.z, A0.w};
  hv[0][2] = f2{B0.x, B0.y}; hv[0][3] = f2{B0.z, B0.w};
  hv[1][0] = f2{A1.x, A1.y}; hv[1][1] = f2{A1.z, A1.w};
  hv[1][2] = f2{B1.x, B1.y}; hv[1][3] = f2{B1.z, B1.w};
}

// ---------- dual-batch packed matvec: ONE weight traversal serves both ----
// Each w[g][k] is read once; two independent fma chains (b=0,1) per read.
// Per-accumulator k-order unchanged -> bitwise-identical results.
__device__ __forceinline__ void mv8p2_first(const f2 (&w)[4][4],
                                            const f2 (&hv)[2][4],
                                            f2 (&a0)[4], f2 (&a1)[4]) {
#pragma unroll
  for (int g = 0; g < 4; ++g) {
    const f2 w0 = w[g][0];
    a0[g] = pk_mul(w0, hv[0][0]);
    a1[g] = pk_mul(w0, hv[1][0]);
#pragma unroll
    for (int k = 1; k < 4; ++k) {
      const f2 wk = w[g][k];
      a0[g] = pk_fma(wk, hv[0][k], a0[g]);
      a1[g] = pk_fma(wk, hv[1][k], a1[g]);
    }
  }
}
__device__ __forceinline__ void mv8p2(const f2 (&w)[4][4],
                                      const f2 (&hv)[2][4],
                                      f2 (&a0)[4], f2 (&a1)[4]) {
#pragma unroll
  for (int g = 0; g < 4; ++g) {
#pragma unroll
    for (int k = 0; k < 4; ++k) {
      const f2 wk = w[g][k];
      a0[g] = pk_fma(wk, hv[0][k], a0[g]);
      a1[g] = pk_fma(wk, hv[1][k], a1[g]);
    }
  }
}

// Dual-batch reduce+select: quad-reduce both batches, select lane's gate
// (gl; reversed order in quad1), one mirror exchange ships the other quad's
// partial for the lane's assigned batch. own + dpp(send) is bitwise the
// original pair-sum.
__device__ __forceinline__ float redsel2(const f2 (&A)[4], const f2 (&B)[4],
                                         bool kb0, bool kb1, bool bsel) {
  float a[4], b[4];
#pragma unroll
  for (int g = 0; g < 4; ++g) { a[g] = A[g].x + A[g].y; b[g] = B[g].x + B[g].y; }
#pragma unroll
  for (int g = 0; g < 4; ++g) {
    a[g] = dpp_add<0xB1>(a[g]);   // quad_perm(1,0,3,2) = xor1
    a[g] = dpp_add<0x4E>(a[g]);   // quad_perm(2,3,0,1) = xor2
    b[g] = dpp_add<0xB1>(b[g]);
    b[g] = dpp_add<0x4E>(b[g]);
  }
  const float t0 = kb1 ? (kb0 ? a[3] : a[2]) : (kb0 ? a[1] : a[0]);  // b0, gate gl
  const float t1 = kb1 ? (kb0 ? b[3] : b[2]) : (kb0 ? b[1] : b[0]);  // b1, gate gl
  const float send = bsel ? t0 : t1;
  const float own  = bsel ? t1 : t0;
  return mirror_add(send, own);
}

// Single-batch finish per lane (lane's batch = its quad). Quad0 gates
// (i,f,g,o) at lanes (0,1,2,3); quad1 reversed -> bsel-selected operands.
__device__ __forceinline__ float gate_finish2(float pre, float kact, float aact,
                                              float bact, float& c, bool bsel) {
  const float e = fast_exp2(kact * pre);
  const float r = fast_rcp(1.0f + e);
  const float a = fmaf(aact, r, bact);
  const float u0 = dpp_mov<0x00>(a);    // quad_perm(0,0,0,0)
  const float u1 = dpp_mov<0x55>(a);    // quad_perm(1,1,1,1)
  const float u2 = dpp_mov<0xAA>(a);    // quad_perm(2,2,2,2)
  const float u3 = dpp_mov<0xFF>(a);    // quad_perm(3,3,3,3)
  const float prod = bsel ? (u3 * u1) : (u0 * u2);   // a_i * a_g
  const float vf   = bsel ? u2 : u1;                 // a_f
  const float vo   = bsel ? u0 : u3;                 // a_o
  c = fmaf(vf, c, prod);
  const float te = fast_exp2(2.8853900817779268f * c);   // tanh(c)
  const float tr = fast_rcp(1.0f + te);
  const float t = vo * tr;
  return fmaf(-2.0f, t, vo);            // o * tanh(c)
}

// One DIAGONAL superstep: h0(s), h1(s-1), h2(s-2). All matvecs read parity
// CUR; results write parity NXT; single LDS barrier at the end. A0/A1/A2 are
// compile-time activity flags (fill/drain peeled outside the steady loop).
// Matvec phase walks weight matrices ONCE, source-layer by source-layer.
template <int CUR, int NXT, bool A0, bool A1, bool A2>
__device__ __forceinline__ void lstm_step(
    float (&hb)[2][3][NB][HS],
    const f2 (&whh0)[4][4], const f2 (&wih1)[4][4],
    const f2 (&whh1)[4][4], const f2 (&wih2)[4][4],
    const f2 (&whh2)[4][4],
    const float (&wi0l)[4],   // per-lane Wih0 row (gate gl)
    float b0l, float b1l, float b2l,
    float kact, float aact, float bact,
    float& c0, float& c1, float& c2,
    const float (&xin)[4],    // lane's batch x(s)
    int j, int k0, int bi,
    bool kb0, bool kb1, bool bsel, bool wq) {
  f2 p0[NB][4], p1[NB][4], p2[NB][4];
  // ---- matvecs grouped by SOURCE layer; each weight read once ----
  {
    f2 hv[2][4];
    ld8x2(&hb[CUR][0][0][k0], &hb[CUR][0][1][k0], hv);   // h0(s-1), both b
    mv8p2_first(whh0, hv, p0[0], p0[1]);                 // L0 recurrent
    mv8p2_first(wih1, hv, p1[0], p1[1]);                 // L1 input
  }
  {
    f2 hv[2][4];
    ld8x2(&hb[CUR][1][0][k0], &hb[CUR][1][1][k0], hv);   // h1(s-2), both b
    mv8p2      (whh1, hv, p1[0], p1[1]);                 // L1 recurrent
    mv8p2_first(wih2, hv, p2[0], p2[1]);                 // L2 input
  }
  {
    f2 hv[2][4];
    ld8x2(&hb[CUR][2][0][k0], &hb[CUR][2][1][k0], hv);   // h2(s-3), both b
    mv8p2      (whh2, hv, p2[0], p2[1]);                 // L2 recurrent
  }
  // ---- finish: one chain per layer per lane (lane's batch) ----
  if (A0) {
    const float s = redsel2(p0[0], p0[1], kb0, kb1, bsel);
    float d = b0l;
#pragma unroll
    for (int f = 0; f < 4; ++f) d = fmaf(wi0l[f], xin[f], d);
    float cc = c0;
    const float h = gate_finish2(s + d, kact, aact, bact, cc, bsel);
    c0 = cc;
    if (wq) hb[NXT][0][bi][j] = h;
  }
  if (A1) {
    const float s = redsel2(p1[0], p1[1], kb0, kb1, bsel);
    float cc = c1;
    const float h = gate_finish2(s + b1l, kact, aact, bact, cc, bsel);
    c1 = cc;
    if (wq) hb[NXT][1][bi][j] = h;
  }
  if (A2) {
    const float s = redsel2(p2[0], p2[1], kb0, kb1, bsel);
    float cc = c2;
    const float h = gate_finish2(s + b2l, kact, aact, bact, cc, bsel);
    c2 = cc;
    if (wq) hb[NXT][2][bi][j] = h;
  }
  lds_barrier();  // single barrier per superstep (LDS-only)
}

__global__ void __launch_bounds__(NT, 2)
lstm3_kernel(const float* __restrict__ x,
             const float* __restrict__ Wih0, const float* __restrict__ Whh0,
             const float* __restrict__ bih0, const float* __restrict__ bhh0,
             const float* __restrict__ Wih1, const float* __restrict__ Whh1,
             const float* __restrict__ bih1, const float* __restrict__ bhh1,
             const float* __restrict__ Wih2, const float* __restrict__ Whh2,
             const float* __restrict__ bih2, const float* __restrict__ bhh2,
             const float* __restrict__ fcw, const float* __restrict__ fcb,
             float* __restrict__ out) {
  __shared__ __align__(16) float hb[2][3][NB][HS];  // [parity][layer][b][k]
  const int tid = threadIdx.x;
  const int j = tid >> 3;       // hidden unit 0..63
  const int ko = tid & 7;       // K-octant (lane bits 0..2)
  const int k0 = ko << 3;
  const int bbase = blockIdx.x * NB;
  // Lane's gate after the quad reduce (quad1 reversed for the mirror pairing)
  const int gl = (ko & 4) ? (3 - (ko & 3)) : (ko & 3);
  const bool kb0 = (gl & 1) != 0;
  const bool kb1 = (gl & 2) != 0;
  const int  bi   = (ko >> 2) & 1;    // lane's batch element
  const bool bsel = bi != 0;
  const bool wq   = (ko & 3) == 0;    // one writer lane per quad

  // register-resident weights: 4 gate-rows x 8-wide K slice per matrix
  f2 whh0[4][4], wih1[4][4], whh1[4][4], wih2[4][4], whh2[4][4];
#pragma unroll
  for (int g = 0; g < 4; ++g) {
    const int r = (g << 6) + j;   // PyTorch gate-order rows: i,f,g,o
    const int ro = (r << 6) + k0;
#define LDW(dst, srcp)                                            \
    {                                                             \
      const float4 A = *(const float4*)&(srcp)[ro];               \
      const float4 B = *(const float4*)&(srcp)[ro + 4];           \
      dst[g][0] = f2{A.x, A.y}; dst[g][1] = f2{A.z, A.w};         \
      dst[g][2] = f2{B.x, B.y}; dst[g][3] = f2{B.z, B.w};         \
    }
    LDW(whh0, Whh0)
    LDW(wih1, Wih1)
    LDW(whh1, Whh1)
    LDW(wih2, Wih2)
    LDW(whh2, Whh2)
#undef LDW
  }

  // per-lane gate-specific constants (gate = gl)
  const int rl = (gl << 6) + j;
  const float b0l = bih0[rl] + bhh0[rl];
  const float b1l = bih1[rl] + bhh1[rl];
  const float b2l = bih2[rl] + bhh2[rl];
  float wi0l[4];
  {
    const float4 w0 = *(const float4*)&Wih0[rl * 4];
    wi0l[0] = w0.x; wi0l[1] = w0.y; wi0l[2] = w0.z; wi0l[3] = w0.w;
  }
  const bool isg = (gl == 2);
  const float kact = isg ? 2.8853900817779268f : -1.4426950408889634f;
  const float aact = isg ? -2.0f : 1.0f;
  const float bact = isg ? 1.0f : 0.0f;

  float c0 = 0.f, c1 = 0.f, c2 = 0.f;   // c-state for the lane's batch

  {  // zero both parities of h (fill steps read zeros for upper layers)
    float* p = &hb[0][0][0][0];
    for (int i = tid; i < 2 * 3 * NB * HS; i += NT) p[i] = 0.f;
  }

  // x prefetch: lane's batch only, double-buffered
  const float* xlane = &x[(size_t)(bbase + bi) * SS * 4];
  float xc[4], xn[4];
  {
    const float4 v = *(const float4*)xlane;
    xc[0] = v.x; xc[1] = v.y; xc[2] = v.z; xc[3] = v.w;
  }
  __syncthreads();

#define LOADX(dst, idx)                                           \
  {                                                               \
    const float4 v = *(const float4*)&xlane[(idx) * 4];           \
    dst[0] = v.x; dst[1] = v.y; dst[2] = v.z; dst[3] = v.w;       \
  }
#define STEP(CUR, NXT, A0, A1, A2, xv)                                       \
  lstm_step<CUR, NXT, A0, A1, A2>(hb, whh0, wih1, whh1, wih2, whh2, wi0l,    \
                                  b0l, b1l, b2l, kact, aact, bact,           \
                                  c0, c1, c2, xv, j, k0, bi, kb0, kb1,       \
                                  bsel, wq)

  // Supersteps s=0..SS+1 (diagonal pipeline; 2 fill + 2 drain peeled).
  // s=0:
  LOADX(xn, 1)
  STEP(0, 1, true, false, false, xc);
  LOADX(xc, 2)
  // s=1:
  STEP(1, 0, true, true, false, xn);
  // steady: s=2..SS-1 (all layers active), 1023 iterations
#pragma unroll 1
  for (int t = 2; t < SS; t += 2) {
    LOADX(xn, t + 1)
    STEP(0, 1, true, true, true, xc);
    const int tp = (t + 2 < SS) ? (t + 2) : (SS - 1);
    LOADX(xc, tp)
    STEP(1, 0, true, true, true, xn);
  }
  // s=SS (L1 last + L2):
  STEP(0, 1, false, true, true, xc);
  // s=SS+1 (L2 last): writes h2(SS-1) into parity 0
  STEP(1, 0, false, false, true, xn);
  __syncthreads();

  // fc: out[b][o] = fc_b[o] + sum_j fc_w[o][j] * h2_last[b][j]
  if (tid < NB * 2) {
    const int b = tid >> 1, o = tid & 1;
    float s = fcb[o];
#pragma unroll
    for (int jj = 0; jj < 64; ++jj)
      s = fmaf(fcw[o * 64 + jj], hb[0][2][b][jj], s);
    out[(bbase + b) * 2 + o] = s;
  }
#undef LOADX
#undef STEP
}

extern "C" void kernel_launch(void* const* d_in, const int* in_sizes, int n_in,
                              void* d_out, int out_size, void* d_ws, size_t ws_size,
                              hipStream_t stream) {
  const float* x    = (const float*)d_in[0];
  const float* Wih0 = (const float*)d_in[1];
  const float* Whh0 = (const float*)d_in[2];
  const float* bih0 = (const float*)d_in[3];
  const float* bhh0 = (const float*)d_in[4];
  const float* Wih1 = (const float*)d_in[5];
  const float* Whh1 = (const float*)d_in[6];
  const float* bih1 = (const float*)d_in[7];
  const float* bhh1 = (const float*)d_in[8];
  const float* Wih2 = (const float*)d_in[9];
  const float* Whh2 = (const float*)d_in[10];
  const float* bih2 = (const float*)d_in[11];
  const float* bhh2 = (const float*)d_in[12];
  const float* fcw  = (const float*)d_in[13];
  const float* fcb  = (const float*)d_in[14];
  float* out = (float*)d_out;

  lstm3_kernel<<<dim3(BATCH / NB), dim3(NT), 0, stream>>>(
      x, Wih0, Whh0, bih0, bhh0, Wih1, Whh1, bih1, bhh1,
      Wih2, Whh2, bih2, bhh2, fcw, fcb, out);
}

// Round 9
// 2843.641 us; speedup vs baseline: 6.8385x; 1.0032x over previous
//
#include <hip/hip_runtime.h>

#define SS 2048
#define BATCH 512
#define NB 2          // batch elements per block
#define NT 512        // threads per block: 64 j * 8 ko
#define HS 72         // h-row stride in floats: 288B keeps float4 alignment,
                      // bank offset 8 between batches -> write banks disjoint

typedef float f2 __attribute__((ext_vector_type(2)));

// ---------- fast fp32 helpers ----------
__device__ __forceinline__ float fast_rcp(float a) { return __builtin_amdgcn_rcpf(a); }
__device__ __forceinline__ float fast_exp2(float a) { return __builtin_amdgcn_exp2f(a); }

// ---------- packed fp32 via native vector ops (-> v_pk_fma_f32) ----------
__device__ __forceinline__ f2 pk_fma(f2 a, f2 b, f2 c) {
  return __builtin_elementwise_fma(a, b, c);
}
__device__ __forceinline__ f2 pk_mul(f2 a, f2 b) { return a * b; }

// ---------- DPP helpers ----------
template <int CTRL>
__device__ __forceinline__ float dpp_add(float v) {
  const int sh = __builtin_amdgcn_update_dpp(0, __float_as_int(v), CTRL, 0xf, 0xf, true);
  return v + __int_as_float(sh);
}
__device__ __forceinline__ float mirror_add(float s, float o) {
  const int sh = __builtin_amdgcn_update_dpp(0, __float_as_int(s), 0x141, 0xf, 0xf, true);
  return o + __int_as_float(sh);
}
template <int CTRL>
__device__ __forceinline__ float dpp_mov(float v) {
  return __int_as_float(__builtin_amdgcn_mov_dpp(__float_as_int(v), CTRL, 0xf, 0xf, true));
}

// ---------- LDS-only barrier (skip the vmcnt drain of __syncthreads) ----------
__device__ __forceinline__ void lds_barrier() {
  asm volatile("s_waitcnt lgkmcnt(0)\n\ts_barrier" ::: "memory");
}

// ---------- load one layer's 8-wide h slice for BOTH batches ----------
__device__ __forceinline__ void ld8x2(const float* p0, const float* p1,
                                      f2 (&hv)[2][4]) {
  const float4 A0 = *(const float4*)p0;
  const float4 B0 = *(const float4*)(p0 + 4);
  const float4 A1 = *(const float4*)p1;
  const float4 B1 = *(const float4*)(p1 + 4);
  hv[0][0] = f2{A0.x, A0.y}; hv[0][1] = f2{A0.z, A0.w};
  hv[0][2] = f2{B0.x, B0.y}; hv[0][3] = f2{B0.z, B0.w};
  hv[1][0] = f2{A1.x, A1.y}; hv[1][1] = f2{A1.z, A1.w};
  hv[1][2] = f2{B1.x, B1.y}; hv[1][3] = f2{B1.z, B1.w};
}

// ---------- dual-batch packed matvec: ONE weight traversal serves both ----
__device__ __forceinline__ void mv8p2_first(const f2 (&w)[4][4],
                                            const f2 (&hv)[2][4],
                                            f2 (&a0)[4], f2 (&a1)[4]) {
#pragma unroll
  for (int g = 0; g < 4; ++g) {
    const f2 w0 = w[g][0];
    a0[g] = pk_mul(w0, hv[0][0]);
    a1[g] = pk_mul(w0, hv[1][0]);
#pragma unroll
    for (int k = 1; k < 4; ++k) {
      const f2 wk = w[g][k];
      a0[g] = pk_fma(wk, hv[0][k], a0[g]);
      a1[g] = pk_fma(wk, hv[1][k], a1[g]);
    }
  }
}
__device__ __forceinline__ void mv8p2(const f2 (&w)[4][4],
                                      const f2 (&hv)[2][4],
                                      f2 (&a0)[4], f2 (&a1)[4]) {
#pragma unroll
  for (int g = 0; g < 4; ++g) {
#pragma unroll
    for (int k = 0; k < 4; ++k) {
      const f2 wk = w[g][k];
      a0[g] = pk_fma(wk, hv[0][k], a0[g]);
      a1[g] = pk_fma(wk, hv[1][k], a1[g]);
    }
  }
}

// Dual-batch reduce+select: quad-reduce both batches, select lane's gate
// (gl; reversed order in quad1), one mirror exchange ships the other quad's
// partial for the lane's assigned batch. own + dpp(send) is bitwise the
// original pair-sum.
__device__ __forceinline__ float redsel2(const f2 (&A)[4], const f2 (&B)[4],
                                         bool kb0, bool kb1, bool bsel) {
  float a[4], b[4];
#pragma unroll
  for (int g = 0; g < 4; ++g) { a[g] = A[g].x + A[g].y; b[g] = B[g].x + B[g].y; }
#pragma unroll
  for (int g = 0; g < 4; ++g) {
    a[g] = dpp_add<0xB1>(a[g]);   // quad_perm(1,0,3,2) = xor1
    a[g] = dpp_add<0x4E>(a[g]);   // quad_perm(2,3,0,1) = xor2
    b[g] = dpp_add<0xB1>(b[g]);
    b[g] = dpp_add<0x4E>(b[g]);
  }
  const float t0 = kb1 ? (kb0 ? a[3] : a[2]) : (kb0 ? a[1] : a[0]);  // b0, gate gl
  const float t1 = kb1 ? (kb0 ? b[3] : b[2]) : (kb0 ? b[1] : b[0]);  // b1, gate gl
  const float send = bsel ? t0 : t1;
  const float own  = bsel ? t1 : t0;
  return mirror_add(send, own);
}

// Single-batch finish per lane (lane's batch = its quad). Quad0 gates
// (i,f,g,o) at lanes (0,1,2,3); quad1 reversed -> bsel-selected operands.
__device__ __forceinline__ float gate_finish2(float pre, float kact, float aact,
                                              float bact, float& c, bool bsel) {
  const float e = fast_exp2(kact * pre);
  const float r = fast_rcp(1.0f + e);
  const float a = fmaf(aact, r, bact);
  const float u0 = dpp_mov<0x00>(a);    // quad_perm(0,0,0,0)
  const float u1 = dpp_mov<0x55>(a);    // quad_perm(1,1,1,1)
  const float u2 = dpp_mov<0xAA>(a);    // quad_perm(2,2,2,2)
  const float u3 = dpp_mov<0xFF>(a);    // quad_perm(3,3,3,3)
  const float prod = bsel ? (u3 * u1) : (u0 * u2);   // a_i * a_g
  const float vf   = bsel ? u2 : u1;                 // a_f
  const float vo   = bsel ? u0 : u3;                 // a_o
  c = fmaf(vf, c, prod);
  const float te = fast_exp2(2.8853900817779268f * c);   // tanh(c)
  const float tr = fast_rcp(1.0f + te);
  const float t = vo * tr;
  return fmaf(-2.0f, t, vo);            // o * tanh(c)
}

// One DIAGONAL superstep: h0(s), h1(s-1), h2(s-2). All matvecs read parity
// CUR; results write parity NXT; single LDS barrier at the end. A0/A1/A2 are
// compile-time activity flags (fill/drain peeled outside the steady loop).
// s_setprio(1) biases SIMD issue toward the wave in its dense matvec phase,
// letting it fill the other wave's serial-chain bubbles (waves within a
// block drift apart inside each barrier window -> role diversity exists).
template <int CUR, int NXT, bool A0, bool A1, bool A2>
__device__ __forceinline__ void lstm_step(
    float (&hb)[2][3][NB][HS],
    const f2 (&whh0)[4][4], const f2 (&wih1)[4][4],
    const f2 (&whh1)[4][4], const f2 (&wih2)[4][4],
    const f2 (&whh2)[4][4],
    const float (&wi0l)[4],   // per-lane Wih0 row (gate gl)
    float b0l, float b1l, float b2l,
    float kact, float aact, float bact,
    float& c0, float& c1, float& c2,
    const float (&xin)[4],    // lane's batch x(s)
    int j, int k0, int bi,
    bool kb0, bool kb1, bool bsel, bool wq) {
  f2 p0[NB][4], p1[NB][4], p2[NB][4];
  __builtin_amdgcn_s_setprio(1);
  // ---- matvecs grouped by SOURCE layer; each weight read once ----
  {
    f2 hv[2][4];
    ld8x2(&hb[CUR][0][0][k0], &hb[CUR][0][1][k0], hv);   // h0(s-1), both b
    mv8p2_first(whh0, hv, p0[0], p0[1]);                 // L0 recurrent
    mv8p2_first(wih1, hv, p1[0], p1[1]);                 // L1 input
  }
  {
    f2 hv[2][4];
    ld8x2(&hb[CUR][1][0][k0], &hb[CUR][1][1][k0], hv);   // h1(s-2), both b
    mv8p2      (whh1, hv, p1[0], p1[1]);                 // L1 recurrent
    mv8p2_first(wih2, hv, p2[0], p2[1]);                 // L2 input
  }
  {
    f2 hv[2][4];
    ld8x2(&hb[CUR][2][0][k0], &hb[CUR][2][1][k0], hv);   // h2(s-3), both b
    mv8p2      (whh2, hv, p2[0], p2[1]);                 // L2 recurrent
  }
  __builtin_amdgcn_s_setprio(0);
  // ---- finish: one chain per layer per lane (lane's batch) ----
  if (A0) {
    const float s = redsel2(p0[0], p0[1], kb0, kb1, bsel);
    float d = b0l;
#pragma unroll
    for (int f = 0; f < 4; ++f) d = fmaf(wi0l[f], xin[f], d);
    float cc = c0;
    const float h = gate_finish2(s + d, kact, aact, bact, cc, bsel);
    c0 = cc;
    if (wq) hb[NXT][0][bi][j] = h;
  }
  if (A1) {
    const float s = redsel2(p1[0], p1[1], kb0, kb1, bsel);
    float cc = c1;
    const float h = gate_finish2(s + b1l, kact, aact, bact, cc, bsel);
    c1 = cc;
    if (wq) hb[NXT][1][bi][j] = h;
  }
  if (A2) {
    const float s = redsel2(p2[0], p2[1], kb0, kb1, bsel);
    float cc = c2;
    const float h = gate_finish2(s + b2l, kact, aact, bact, cc, bsel);
    c2 = cc;
    if (wq) hb[NXT][2][bi][j] = h;
  }
  lds_barrier();  // single barrier per superstep (LDS-only)
}

__global__ void __launch_bounds__(NT, 2)
lstm3_kernel(const float* __restrict__ x,
             const float* __restrict__ Wih0, const float* __restrict__ Whh0,
             const float* __restrict__ bih0, const float* __restrict__ bhh0,
             const float* __restrict__ Wih1, const float* __restrict__ Whh1,
             const float* __restrict__ bih1, const float* __restrict__ bhh1,
             const float* __restrict__ Wih2, const float* __restrict__ Whh2,
             const float* __restrict__ bih2, const float* __restrict__ bhh2,
             const float* __restrict__ fcw, const float* __restrict__ fcb,
             float* __restrict__ out) {
  __shared__ __align__(16) float hb[2][3][NB][HS];  // [parity][layer][b][k]
  const int tid = threadIdx.x;
  const int j = tid >> 3;       // hidden unit 0..63
  const int ko = tid & 7;       // K-octant (lane bits 0..2)
  const int k0 = ko << 3;
  const int bbase = blockIdx.x * NB;
  // Lane's gate after the quad reduce (quad1 reversed for the mirror pairing)
  const int gl = (ko & 4) ? (3 - (ko & 3)) : (ko & 3);
  const bool kb0 = (gl & 1) != 0;
  const bool kb1 = (gl & 2) != 0;
  const int  bi   = (ko >> 2) & 1;    // lane's batch element
  const bool bsel = bi != 0;
  const bool wq   = (ko & 3) == 0;    // one writer lane per quad

  // register-resident weights: 4 gate-rows x 8-wide K slice per matrix
  f2 whh0[4][4], wih1[4][4], whh1[4][4], wih2[4][4], whh2[4][4];
#pragma unroll
  for (int g = 0; g < 4; ++g) {
    const int r = (g << 6) + j;   // PyTorch gate-order rows: i,f,g,o
    const int ro = (r << 6) + k0;
#define LDW(dst, srcp)                                            \
    {                                                             \
      const float4 A = *(const float4*)&(srcp)[ro];               \
      const float4 B = *(const float4*)&(srcp)[ro + 4];           \
      dst[g][0] = f2{A.x, A.y}; dst[g][1] = f2{A.z, A.w};         \
      dst[g][2] = f2{B.x, B.y}; dst[g][3] = f2{B.z, B.w};         \
    }
    LDW(whh0, Whh0)
    LDW(wih1, Wih1)
    LDW(whh1, Whh1)
    LDW(wih2, Wih2)
    LDW(whh2, Whh2)
#undef LDW
  }

  // per-lane gate-specific constants (gate = gl)
  const int rl = (gl << 6) + j;
  const float b0l = bih0[rl] + bhh0[rl];
  const float b1l = bih1[rl] + bhh1[rl];
  const float b2l = bih2[rl] + bhh2[rl];
  float wi0l[4];
  {
    const float4 w0 = *(const float4*)&Wih0[rl * 4];
    wi0l[0] = w0.x; wi0l[1] = w0.y; wi0l[2] = w0.z; wi0l[3] = w0.w;
  }
  const bool isg = (gl == 2);
  const float kact = isg ? 2.8853900817779268f : -1.4426950408889634f;
  const float aact = isg ? -2.0f : 1.0f;
  const float bact = isg ? 1.0f : 0.0f;

  float c0 = 0.f, c1 = 0.f, c2 = 0.f;   // c-state for the lane's batch

  {  // zero both parities of h (fill steps read zeros for upper layers)
    float* p = &hb[0][0][0][0];
    for (int i = tid; i < 2 * 3 * NB * HS; i += NT) p[i] = 0.f;
  }

  // x prefetch: lane's batch only, double-buffered
  const float* xlane = &x[(size_t)(bbase + bi) * SS * 4];
  float xc[4], xn[4];
  {
    const float4 v = *(const float4*)xlane;
    xc[0] = v.x; xc[1] = v.y; xc[2] = v.z; xc[3] = v.w;
  }
  __syncthreads();

#define LOADX(dst, idx)                                           \
  {                                                               \
    const float4 v = *(const float4*)&xlane[(idx) * 4];           \
    dst[0] = v.x; dst[1] = v.y; dst[2] = v.z; dst[3] = v.w;       \
  }
#define STEP(CUR, NXT, A0, A1, A2, xv)                                       \
  lstm_step<CUR, NXT, A0, A1, A2>(hb, whh0, wih1, whh1, wih2, whh2, wi0l,    \
                                  b0l, b1l, b2l, kact, aact, bact,           \
                                  c0, c1, c2, xv, j, k0, bi, kb0, kb1,       \
                                  bsel, wq)

  // Supersteps s=0..SS+1 (diagonal pipeline; fill + drain peeled).
  // s=0:
  LOADX(xn, 1)
  STEP(0, 1, true, false, false, xc);
  LOADX(xc, 2)
  // s=1:
  STEP(1, 0, true, true, false, xn);
  // steady: s=2..SS-3 (all layers active), unclamped prefetch
#pragma unroll 1
  for (int t = 2; t < SS - 2; t += 2) {
    LOADX(xn, t + 1)
    STEP(0, 1, true, true, true, xc);
    LOADX(xc, t + 2)
    STEP(1, 0, true, true, true, xn);
  }
  // last steady pair (t = SS-2): the old clamped reload of xc was dead
  // (it only fed A0=false steps) -- dropped.
  LOADX(xn, SS - 1)
  STEP(0, 1, true, true, true, xc);
  STEP(1, 0, true, true, true, xn);
  // s=SS (L1 last + L2); xin unused (A0=false):
  STEP(0, 1, false, true, true, xc);
  // s=SS+1 (L2 last): writes h2(SS-1) into parity 0
  STEP(1, 0, false, false, true, xn);
  __syncthreads();

  // fc: out[b][o] = fc_b[o] + sum_j fc_w[o][j] * h2_last[b][j]
  if (tid < NB * 2) {
    const int b = tid >> 1, o = tid & 1;
    float s = fcb[o];
#pragma unroll
    for (int jj = 0; jj < 64; ++jj)
      s = fmaf(fcw[o * 64 + jj], hb[0][2][b][jj], s);
    out[(bbase + b) * 2 + o] = s;
  }
#undef LOADX
#undef STEP
}

extern "C" void kernel_launch(void* const* d_in, const int* in_sizes, int n_in,
                              void* d_out, int out_size, void* d_ws, size_t ws_size,
                              hipStream_t stream) {
  const float* x    = (const float*)d_in[0];
  const float* Wih0 = (const float*)d_in[1];
  const float* Whh0 = (const float*)d_in[2];
  const float* bih0 = (const float*)d_in[3];
  const float* bhh0 = (const float*)d_in[4];
  const float* Wih1 = (const float*)d_in[5];
  const float* Whh1 = (const float*)d_in[6];
  const float* bih1 = (const float*)d_in[7];
  const float* bhh1 = (const float*)d_in[8];
  const float* Wih2 = (const float*)d_in[9];
  const float* Whh2 = (const float*)d_in[10];
  const float* bih2 = (const float*)d_in[11];
  const float* bhh2 = (const float*)d_in[12];
  const float* fcw  = (const float*)d_in[13];
  const float* fcb  = (const float*)d_in[14];
  float* out = (float*)d_out;

  lstm3_kernel<<<dim3(BATCH / NB), dim3(NT), 0, stream>>>(
      x, Wih0, Whh0, bih0, bhh0, Wih1, Whh1, bih1, bhh1,
      Wih2, Whh2, bih2, bhh2, fcw, fcb, out);
}